// Round 9
// baseline (268.419 us; speedup 1.0000x reference)
//
#include <hip/hip_runtime.h>
#include <stdint.h>

// Attention fwd: B=4 T=2048 D=1024 H=16 Dh=64.
// R17 = R16 (measured 252.4) with ONE delta: gemm_qkv swapped to the R14
//   256x256 8-phase body (verified correct in R6 bench) with
//   __attribute__((amdgpu_waves_per_eu(2,2))). R14/R15 failed because
//   __launch_bounds__ 2nd arg is only a MIN waves/EU — allocator chose 4/EU
//   = 128-VGPR cap -> acc[8][4] spill (WRITE 97MB, MfmaUtil 24). (2,2) pins
//   max too -> 256-VGPR budget, need ~220, no spill. MFMA floor/block 13.7us
//   -> qkv ~40-55us at m201-class util vs ~72 now.
// flash: R9 form + setprio (null, kept for single-delta discipline).
// gemm_o: R9 128x64/1024-block form.

typedef __attribute__((ext_vector_type(8))) short bf16x8;
typedef __attribute__((ext_vector_type(4))) float f32x4;

#define MFMA32 __builtin_amdgcn_mfma_f32_16x16x32_bf16

#if __has_builtin(__builtin_amdgcn_exp2f)
#define EXP2(x) __builtin_amdgcn_exp2f(x)
#else
#define EXP2(x) exp2f(x)   // host pass only
#endif

__device__ __forceinline__ unsigned short f2bf(float f) {
  union { float f; unsigned int u; } v; v.f = f;
  unsigned int r = v.u + 0x7FFFu + ((v.u >> 16) & 1u);  // RNE
  return (unsigned short)(r >> 16);
}

__device__ __forceinline__ void gl_lds16(const void* g, void* l) {
  __builtin_amdgcn_global_load_lds(
      (const __attribute__((address_space(1))) unsigned int*)g,
      (__attribute__((address_space(3))) unsigned int*)l, 16, 0, 0);
}

// truncating pack of two positive fp32 -> one u32 (two bf16)
__device__ __forceinline__ unsigned packbf2(float lo, float hi) {
  union { float f; unsigned u; } a, b; a.f = lo; b.f = hi;
  return __builtin_amdgcn_perm(b.u, a.u, 0x07060302u);
}

// LDS chunk swizzle for K/V tiles (conflict-free for permuted-row b128 reads)
__device__ __forceinline__ int rho(int r) { return (r & 3) | ((r >> 1) & 4); }

// ---------------- merged prep kernel ----------------
__device__ __forceinline__ void conv8(const float* __restrict__ src,
                                      unsigned short* __restrict__ dst, int i) {
  const float4* sp = (const float4*)src;
  float4 a = sp[2 * i], b = sp[2 * i + 1];
  union { unsigned short u[8]; uint4 v; } o;
  o.u[0] = f2bf(a.x); o.u[1] = f2bf(a.y); o.u[2] = f2bf(a.z); o.u[3] = f2bf(a.w);
  o.u[4] = f2bf(b.x); o.u[5] = f2bf(b.y); o.u[6] = f2bf(b.z); o.u[7] = f2bf(b.w);
  ((uint4*)dst)[i] = o.v;
}

__global__ __launch_bounds__(256) void prep_all(
    const float* __restrict__ x, const float* __restrict__ WQ,
    const float* __restrict__ WK, const float* __restrict__ WV,
    const float* __restrict__ WO, unsigned short* __restrict__ Xb,
    unsigned short* __restrict__ Wqkv, unsigned short* __restrict__ Wot) {
  const int bx = blockIdx.x, t = threadIdx.x;
  if (bx < 4096) {
    conv8(x, Xb, bx * 256 + t);
  } else if (bx < 4608) {
    conv8(WQ, Wqkv, (bx - 4096) * 256 + t);
  } else if (bx < 5120) {
    conv8(WK, Wqkv + 1048576, (bx - 4608) * 256 + t);
  } else if (bx < 5632) {
    conv8(WV, Wqkv + 2097152, (bx - 5120) * 256 + t);
  } else {
    // W_O [16][1024][64] fp32 -> Wot [d][h*64+k] bf16
    int tid = (bx - 5632) * 256 + t;
    int h = tid >> 13, rem = tid & 8191;
    int d = rem >> 3, c = rem & 7;
    const float4* sp = (const float4*)(WO + (size_t)h * 65536 + d * 64 + c * 8);
    float4 a = sp[0], e = sp[1];
    union { unsigned short u[8]; uint4 v; } o;
    o.u[0] = f2bf(a.x); o.u[1] = f2bf(a.y); o.u[2] = f2bf(a.z); o.u[3] = f2bf(a.w);
    o.u[4] = f2bf(e.x); o.u[5] = f2bf(e.y); o.u[6] = f2bf(e.z); o.u[7] = f2bf(e.w);
    *(uint4*)(Wot + (size_t)d * 1024 + h * 64 + c * 8) = o.v;
  }
}

// ---------------- QKV projection: 256x256 tile, 8-phase pipelined ------------
// LDS ushort layout: A0 @0 (256x64), B0 @16384, A1 @32768, B1 @49152 (32KB ea).
// Swizzle: element (row,k) at row*64 + ((k>>3)^(row&7))*8 + (k&7)  (involution,
// staged via pre-swizzled global source). 8 waves as 2M x 4N: per-wave 128x64.
// REGISTER REUSE CONTRACT (race-free staging): br[nj][C] holds BOTH K-chunks,
// loaded ph0/ph1 (resp ph4/ph5); ph2/ph3 (ph6/ph7) reuse br from registers so
// the B buffer has NO LDS reads after ph1 (ph5) and can be staged ph2/ph3.

template <int MH, int C>
__device__ __forceinline__ void qkv_ds_a(const unsigned short* A, int wm, int quad,
                                         int l15, bf16x8 ar[4][2]) {
#pragma unroll
  for (int ii = 0; ii < 4; ++ii) {
    int ra = wm * 128 + MH * 64 + ii * 16 + l15;
    ar[ii][C] = *(const bf16x8*)(A + ra * 64 + (((C * 4 + quad) ^ (ra & 7)) * 8));
  }
}

template <int C>
__device__ __forceinline__ void qkv_ds_b(const unsigned short* B, int wn, int quad,
                                         int l15, bf16x8 br[4][2]) {
#pragma unroll
  for (int nj = 0; nj < 4; ++nj) {
    int rb = wn * 64 + nj * 16 + l15;
    br[nj][C] = *(const bf16x8*)(B + rb * 64 + (((C * 4 + quad) ^ (rb & 7)) * 8));
  }
}

template <int MH, int C>
__device__ __forceinline__ void qkv_mf(const bf16x8 ar[4][2], const bf16x8 br[4][2],
                                       f32x4 acc[8][4]) {
#pragma unroll
  for (int ii = 0; ii < 4; ++ii)
#pragma unroll
    for (int nj = 0; nj < 4; ++nj)
      acc[MH * 4 + ii][nj] =
          MFMA32(ar[ii][C], br[nj][C], acc[MH * 4 + ii][nj], 0, 0, 0);
}

#define QKV_BAR() __builtin_amdgcn_s_barrier()
#define QKV_LGKM0() asm volatile("s_waitcnt lgkmcnt(0)" ::: "memory")
#define SA_(bb, kt, u) \
  gl_lds16(Xb + (size_t)aoff[u] + (size_t)(kt) * 64, lds + (bb)*32768 + adst[u])
#define SB_(bb, kt, u) \
  gl_lds16(Wqkv + (size_t)boff[u] + (size_t)(kt) * 64, lds + (bb)*32768 + 16384 + bdst[u])

__global__ __attribute__((amdgpu_waves_per_eu(2, 2))) __launch_bounds__(512)
void gemm_qkv(
    const unsigned short* __restrict__ Xb, const unsigned short* __restrict__ Wqkv,
    const float* __restrict__ bQ, const float* __restrict__ bK,
    const float* __restrict__ bV, unsigned short* __restrict__ Qg,
    unsigned short* __restrict__ Kg, unsigned int* __restrict__ Vpg) {
  __shared__ unsigned short lds[65536];  // 128 KB
  const int tid = threadIdx.x, lane = tid & 63, w = tid >> 6;
  const int quad = lane >> 4, l15 = lane & 15;
  const int wm = w >> 2, wn = w & 3;
  const int m0 = blockIdx.x * 256, n0 = blockIdx.y * 256;

  // staging source offsets (inverse-swizzled global address; LDS dest linear)
  int aoff[4], adst[4], boff[4], bdst[4];
#pragma unroll
  for (int u = 0; u < 4; ++u) {
    int s = u * 512 + tid, row = s >> 3;
    int cl = ((s & 7) ^ (row & 7)) * 8;
    aoff[u] = (m0 + row) * 1024 + cl;
    boff[u] = (n0 + row) * 1024 + cl;
    adst[u] = s * 8;
    bdst[u] = s * 8;
  }

  const unsigned short* A0 = lds;
  const unsigned short* B0 = lds + 16384;
  const unsigned short* A1 = lds + 32768;
  const unsigned short* B1 = lds + 49152;

  f32x4 acc[8][4];
#pragma unroll
  for (int i = 0; i < 8; ++i)
#pragma unroll
    for (int j = 0; j < 4; ++j) acc[i][j] = (f32x4){0.f, 0.f, 0.f, 0.f};
  bf16x8 ar[4][2], br[4][2];

  // prologue: tile0 full -> buf0 (8 loads); tile1 B -> buf1 (4 loads)
  SA_(0, 0, 0); SA_(0, 0, 1); SA_(0, 0, 2); SA_(0, 0, 3);
  SB_(0, 0, 0); SB_(0, 0, 1); SB_(0, 0, 2); SB_(0, 0, 3);
  SB_(1, 1, 0); SB_(1, 1, 1); SB_(1, 1, 2); SB_(1, 1, 3);
  asm volatile("s_waitcnt vmcnt(4)" ::: "memory");  // tile0 landed; tile1-B in flight
  QKV_BAR();

  // 16 K-tiles of 64; iteration i computes tiles 2i (buf0) and 2i+1 (buf1).
  // Staging (2 loads/phase): ph0/1 A(2i+1)->buf1, ph2/3 B(2i+2)->buf0,
  // ph4/5 A(2i+2)->buf0, ph6/7 B(2i+3)->buf1.
  // vmcnt ledger at ph3-wait: [B1:4][A1:4][B0new:4] -> vmcnt(4) drains A1+B1
  // (read ph4-7); at ph7-wait: [B0n:4][A0n:4][B1n:4] -> vmcnt(4) drains
  // A0n+B0n (read next ph0). Prologue vmcnt(4) drains tile0's 8.
#pragma unroll 1
  for (int i = 0; i < 8; ++i) {
    const int tn = 2 * i + 2;
    const bool st = (i < 7);
    // ph0: buf0 (mh0,c0); loads br[.][0]
    qkv_ds_a<0, 0>(A0, wm, quad, l15, ar);
    qkv_ds_b<0>(B0, wn, quad, l15, br);
    SA_(1, 2 * i + 1, 0); SA_(1, 2 * i + 1, 1);
    QKV_BAR(); QKV_LGKM0();
    __builtin_amdgcn_s_setprio(1); qkv_mf<0, 0>(ar, br, acc); __builtin_amdgcn_s_setprio(0);
    QKV_BAR();
    // ph1: buf0 (mh0,c1); loads br[.][1] — last LDS reads of B0
    qkv_ds_a<0, 1>(A0, wm, quad, l15, ar);
    qkv_ds_b<1>(B0, wn, quad, l15, br);
    SA_(1, 2 * i + 1, 2); SA_(1, 2 * i + 1, 3);
    QKV_BAR(); QKV_LGKM0();
    __builtin_amdgcn_s_setprio(1); qkv_mf<0, 1>(ar, br, acc); __builtin_amdgcn_s_setprio(0);
    QKV_BAR();
    // ph2: buf0 (mh1,c0); br reused from regs; B0 free -> stage into it
    qkv_ds_a<1, 0>(A0, wm, quad, l15, ar);
    if (st) { SB_(0, tn, 0); SB_(0, tn, 1); }
    QKV_BAR(); QKV_LGKM0();
    __builtin_amdgcn_s_setprio(1); qkv_mf<1, 0>(ar, br, acc); __builtin_amdgcn_s_setprio(0);
    QKV_BAR();
    // ph3: buf0 (mh1,c1); counted wait
    qkv_ds_a<1, 1>(A0, wm, quad, l15, ar);
    if (st) { SB_(0, tn, 2); SB_(0, tn, 3); }
    QKV_BAR(); QKV_LGKM0();
    __builtin_amdgcn_s_setprio(1); qkv_mf<1, 1>(ar, br, acc); __builtin_amdgcn_s_setprio(0);
    if (st) asm volatile("s_waitcnt vmcnt(4)" ::: "memory");
    else    asm volatile("s_waitcnt vmcnt(0)" ::: "memory");  // last iter: drain all
    QKV_BAR();
    // ph4: buf1 (mh0,c0); A(buf0) free (reads done ph3)
    qkv_ds_a<0, 0>(A1, wm, quad, l15, ar);
    qkv_ds_b<0>(B1, wn, quad, l15, br);
    if (st) { SA_(0, tn, 0); SA_(0, tn, 1); }
    QKV_BAR(); QKV_LGKM0();
    __builtin_amdgcn_s_setprio(1); qkv_mf<0, 0>(ar, br, acc); __builtin_amdgcn_s_setprio(0);
    QKV_BAR();
    // ph5: buf1 (mh0,c1) — last LDS reads of B1
    qkv_ds_a<0, 1>(A1, wm, quad, l15, ar);
    qkv_ds_b<1>(B1, wn, quad, l15, br);
    if (st) { SA_(0, tn, 2); SA_(0, tn, 3); }
    QKV_BAR(); QKV_LGKM0();
    __builtin_amdgcn_s_setprio(1); qkv_mf<0, 1>(ar, br, acc); __builtin_amdgcn_s_setprio(0);
    QKV_BAR();
    // ph6: buf1 (mh1,c0); br reused; B1 free -> stage into it
    qkv_ds_a<1, 0>(A1, wm, quad, l15, ar);
    if (st) { SB_(1, tn + 1, 0); SB_(1, tn + 1, 1); }
    QKV_BAR(); QKV_LGKM0();
    __builtin_amdgcn_s_setprio(1); qkv_mf<1, 0>(ar, br, acc); __builtin_amdgcn_s_setprio(0);
    QKV_BAR();
    // ph7: buf1 (mh1,c1); counted wait
    qkv_ds_a<1, 1>(A1, wm, quad, l15, ar);
    if (st) { SB_(1, tn + 1, 2); SB_(1, tn + 1, 3); }
    QKV_BAR(); QKV_LGKM0();
    __builtin_amdgcn_s_setprio(1); qkv_mf<1, 1>(ar, br, acc); __builtin_amdgcn_s_setprio(0);
    asm volatile("s_waitcnt vmcnt(4)" ::: "memory");
    QKV_BAR();
  }

  // epilogue: C[row = m0+wm*128+mi*16+quad*4+r][col = n0+wn*64+nj*16+l15]
#pragma unroll
  for (int nj = 0; nj < 4; ++nj) {
    const int n_abs = n0 + wn * 64 + nj * 16 + l15;  // 0..3071
    const int type = n_abs >> 10;                    // 0=Q 1=K 2=V
    const int n_in = n_abs & 1023;
    const int h = n_in >> 6, kh = n_in & 63;
    const float bv = ((type == 0) ? bQ : (type == 1) ? bK : bV)[n_in];
#pragma unroll
    for (int mi = 0; mi < 8; ++mi) {
      const int mb = m0 + wm * 128 + mi * 16 + quad * 4;
      const int b = mb >> 11, tb = mb & 2047;
      if (type == 2) {
        uint2 pk;
        pk.x = (unsigned)f2bf(acc[mi][nj][0] + bv) |
               ((unsigned)f2bf(acc[mi][nj][1] + bv) << 16);
        pk.y = (unsigned)f2bf(acc[mi][nj][2] + bv) |
               ((unsigned)f2bf(acc[mi][nj][3] + bv) << 16);
        *(uint2*)(Vpg + ((size_t)(b * 16 + h) * 64 + kh) * 1024 + (tb >> 1)) = pk;
      } else {
        unsigned short* dst =
            ((type == 0) ? Qg : Kg) + ((size_t)(b * 16 + h) * 2048 + tb) * 64 + kh;
        // Q pre-scaled by 1/sqrt(Dh) * log2(e) so flash uses exp2 directly
        const float sc = (type == 0) ? 0.18033688011112042f : 1.0f;
        dst[0]   = f2bf((acc[mi][nj][0] + bv) * sc);
        dst[64]  = f2bf((acc[mi][nj][1] + bv) * sc);
        dst[128] = f2bf((acc[mi][nj][2] + bv) * sc);
        dst[192] = f2bf((acc[mi][nj][3] + bv) * sc);
      }
    }
  }
}

#undef SA_
#undef SB_
#undef QKV_BAR
#undef QKV_LGKM0

// ---------------- flash attention (R9 form + T5 setprio on PV) --------------
__device__ __forceinline__ void stage_kv(const unsigned short* __restrict__ Kb,
                                         const unsigned int* __restrict__ Vb,
                                         unsigned short* smem, int tid, int s0, int b) {
#pragma unroll
  for (int u = 0; u < 2; ++u) {
    int s = u * 256 + tid, row = s >> 3, g = (s & 7) ^ rho(row);
    gl_lds16(Kb + (size_t)(s0 + row) * 64 + g * 8, smem + b * 8192 + s * 8);
    gl_lds16(Vb + (size_t)row * 1024 + (s0 >> 1) + g * 4,
             smem + b * 8192 + 4096 + s * 8);
  }
}

// block: 256 q-rows of one (b,h); wave owns 64 q; k-tiles of 64, double-buffered.
// grid (bh=64, qt=8): all q-tiles of one bh on one XCD -> K/V L2-local.
__global__ __launch_bounds__(256, 2) void flash_attn(
    const unsigned short* __restrict__ Qg, const unsigned short* __restrict__ Kg,
    const unsigned int* __restrict__ Vpg, unsigned short* __restrict__ OH) {
  __shared__ unsigned short smem[16384];  // 32KB: [K0 8K][V0 8K][K1 8K][V1 8K]
  const int tid = threadIdx.x, lane = tid & 63, w = tid >> 6;
  const int quad = lane >> 4, l15 = lane & 15;
  const int bh = blockIdx.x, qt = blockIdx.y;

  const unsigned short* Qb = Qg + ((size_t)bh * 2048 + qt * 256) * 64;
  const unsigned short* Kb = Kg + (size_t)bh * 2048 * 64;
  const unsigned int*  Vb = Vpg + (size_t)bh * 64 * 1024;

  // stage Q (256 rows = 32KB, whole smem) — dead before tile 0
#pragma unroll
  for (int u = 0; u < 8; ++u) {
    int s = u * 256 + tid, row = s >> 3;
    gl_lds16(Qb + row * 64 + ((s & 7) ^ (row & 7)) * 8, smem + s * 8);
  }
  __syncthreads();

  bf16x8 qf[4][2];  // B-operand Q frags, hoisted for whole kernel
#pragma unroll
  for (int qi = 0; qi < 4; ++qi) {
    int row = w * 64 + qi * 16 + l15;
#pragma unroll
    for (int c = 0; c < 2; ++c)
      qf[qi][c] = *(const bf16x8*)(smem + row * 64 + (((c * 4 + quad) ^ (row & 7)) * 8));
  }
  __syncthreads();  // all waves done reading Q; safe to overwrite with K0/V0

  stage_kv(Kb, Vb, smem, tid, 0, 0);

  f32x4 o[4][4];
  float l_part[4] = {0.f, 0.f, 0.f, 0.f};
#pragma unroll
  for (int qi = 0; qi < 4; ++qi)
#pragma unroll
    for (int nj = 0; nj < 4; ++nj) o[qi][nj] = (f32x4){0.f, 0.f, 0.f, 0.f};

  for (int t = 0; t < 32; ++t) {
    __syncthreads();  // drains tile-t staging
    if (t < 31) stage_kv(Kb, Vb, smem, tid, (t + 1) * 64, (t + 1) & 1);
    const unsigned short* Kd = smem + (t & 1) * 8192;
    const unsigned short* Vd = Kd + 4096;

#pragma unroll
    for (int blk = 0; blk < 2; ++blk) {
      // V B-frags: Vt[dh = nj*16+l15][s = blk*32 + quad*8 .. +7] — one b128 each
      bf16x8 vb[4];
#pragma unroll
      for (int nj = 0; nj < 4; ++nj) {
        int vrow = nj * 16 + l15;
        vb[nj] = *(const bf16x8*)(Vd + vrow * 64 + (((blk * 4 + quad) ^ rho(vrow)) * 8));
      }
      union { unsigned u[4]; bf16x8 v; } pa[4];
#pragma unroll
      for (int v = 0; v < 2; ++v) {
        // permuted K rows: C/D row m maps to s = blk*32 + 8*quad + 4*v + reg
        int krow = blk * 32 + 8 * (l15 >> 2) + 4 * v + (l15 & 3);
        const unsigned short* kr = Kd + krow * 64;
        bf16x8 ka0 = *(const bf16x8*)(kr + ((quad ^ rho(krow)) * 8));
        bf16x8 ka1 = *(const bf16x8*)(kr + (((4 + quad) ^ rho(krow)) * 8));
#pragma unroll
        for (int qi = 0; qi < 4; ++qi) {
          f32x4 S = (f32x4){0.f, 0.f, 0.f, 0.f};
          S = MFMA32(ka0, qf[qi][0], S, 0, 0, 0);
          S = MFMA32(ka1, qf[qi][1], S, 0, 0, 0);
          float e0 = EXP2(S[0]), e1 = EXP2(S[1]), e2 = EXP2(S[2]), e3 = EXP2(S[3]);
          l_part[qi] += (e0 + e1) + (e2 + e3);
          pa[qi].u[2 * v] = packbf2(e0, e1);
          pa[qi].u[2 * v + 1] = packbf2(e2, e3);
        }
      }
      // T5: boost this wave while it drains the 16-MFMA PV cluster (m191)
      __builtin_amdgcn_s_setprio(1);
#pragma unroll
      for (int nj = 0; nj < 4; ++nj)
#pragma unroll
        for (int qi = 0; qi < 4; ++qi)
          o[qi][nj] = MFMA32(pa[qi].v, vb[nj], o[qi][nj], 0, 0, 0);
      __builtin_amdgcn_s_setprio(0);
    }
  }

  // l: cross-quad reduce once; normalize + store
  const int b = bh >> 4, h = bh & 15;
#pragma unroll
  for (int qi = 0; qi < 4; ++qi) {
    float l = l_part[qi];
    l += __shfl_xor(l, 16);
    l += __shfl_xor(l, 32);
    float linv = 1.0f / l;
#pragma unroll
    for (int r = 0; r < 4; ++r) {
      float lr = __shfl(linv, 4 * quad + r);  // l of q_local = 4*quad + r
      int trow = qt * 256 + w * 64 + qi * 16 + 4 * quad + r;
#pragma unroll
      for (int nj = 0; nj < 4; ++nj) {
        int col = h * 64 + nj * 16 + l15;
        OH[((size_t)b * 2048 + trow) * 1024 + col] = f2bf(o[qi][nj][r] * lr);
      }
    }
  }
}

// ---------------- output projection (128x64 tile, R9 form) ----------------
__global__ __launch_bounds__(256) void gemm_o(
    const unsigned short* __restrict__ OHm, const unsigned short* __restrict__ Wot,
    const float* __restrict__ bO, float* __restrict__ Out) {
  __shared__ unsigned short As[128 * 64];  // 16KB
  __shared__ unsigned short Bs[64 * 64];   // 8KB
  const int tid = threadIdx.x, lane = tid & 63, w = tid >> 6;
  const int quad = lane >> 4, l15 = lane & 15;
  const int wm = w & 1, wn = w >> 1;
  const int m0 = blockIdx.x * 128, n0 = blockIdx.y * 64;
  f32x4 acc[4][2];
#pragma unroll
  for (int i = 0; i < 4; ++i)
#pragma unroll
    for (int j = 0; j < 2; ++j) acc[i][j] = (f32x4){0.f, 0.f, 0.f, 0.f};

  for (int k0 = 0; k0 < 1024; k0 += 64) {
    __syncthreads();
#pragma unroll
    for (int u = 0; u < 4; ++u) {
      int s = u * 256 + tid, row = s >> 3;
      int cl = ((s & 7) ^ (row & 7)) * 8;
      gl_lds16(OHm + (size_t)(m0 + row) * 1024 + k0 + cl, As + s * 8);
    }
#pragma unroll
    for (int u = 0; u < 2; ++u) {
      int s = u * 256 + tid, row = s >> 3;
      int cl = ((s & 7) ^ (row & 7)) * 8;
      gl_lds16(Wot + (size_t)(n0 + row) * 1024 + k0 + cl, Bs + s * 8);
    }
    __syncthreads();
    bf16x8 af[4][2], bfr[2][2];
#pragma unroll
    for (int i = 0; i < 4; ++i) {
      int ra = wm * 64 + i * 16 + l15;
#pragma unroll
      for (int c = 0; c < 2; ++c)
        af[i][c] = *(const bf16x8*)(As + ra * 64 + (((c * 4 + quad) ^ (ra & 7)) * 8));
    }
#pragma unroll
    for (int j = 0; j < 2; ++j) {
      int rb = wn * 32 + j * 16 + l15;
#pragma unroll
      for (int c = 0; c < 2; ++c)
        bfr[j][c] = *(const bf16x8*)(Bs + rb * 64 + (((c * 4 + quad) ^ (rb & 7)) * 8));
    }
#pragma unroll
    for (int mi = 0; mi < 4; ++mi)
#pragma unroll
      for (int nj = 0; nj < 2; ++nj) {
        acc[mi][nj] = MFMA32(af[mi][0], bfr[nj][0], acc[mi][nj], 0, 0, 0);
        acc[mi][nj] = MFMA32(af[mi][1], bfr[nj][1], acc[mi][nj], 0, 0, 0);
      }
  }

#pragma unroll
  for (int nj = 0; nj < 2; ++nj) {
    const int n = n0 + wn * 32 + nj * 16 + l15;
    const float bv = bO[n];
#pragma unroll
    for (int mi = 0; mi < 4; ++mi) {
      const int mb = m0 + wm * 64 + mi * 16 + quad * 4;
#pragma unroll
      for (int r = 0; r < 4; ++r)
        Out[(size_t)(mb + r) * 1024 + n] = acc[mi][nj][r] + bv;
    }
  }
}

// ---------------- launch ----------------
extern "C" void kernel_launch(void* const* d_in, const int* in_sizes, int n_in,
                              void* d_out, int out_size, void* d_ws, size_t ws_size,
                              hipStream_t stream) {
  const float* x  = (const float*)d_in[0];
  const float* WQ = (const float*)d_in[1];
  const float* bQ = (const float*)d_in[2];
  const float* WK = (const float*)d_in[3];
  const float* bK = (const float*)d_in[4];
  const float* WV = (const float*)d_in[5];
  const float* bV = (const float*)d_in[6];
  const float* WO = (const float*)d_in[7];
  const float* bO = (const float*)d_in[8];
  float* out = (float*)d_out;

  char* ws = (char*)d_ws;
  unsigned short* Xb   = (unsigned short*)(ws);                // 16 MB
  unsigned short* OH   = (unsigned short*)(ws);                // alias (Xb dead)
  unsigned short* Wqkv = (unsigned short*)(ws + 16777216);     // 6 MB
  unsigned short* Wot  = (unsigned short*)(ws + 23068672);     // 2 MB
  unsigned short* Qg   = (unsigned short*)(ws + 25165824);     // 16 MB
  unsigned short* Kg   = (unsigned short*)(ws + 41943040);     // 16 MB
  unsigned int*   Vpg  = (unsigned int*)  (ws + 58720256);     // 16 MB

  prep_all<<<6144, 256, 0, stream>>>(x, WQ, WK, WV, WO, Xb, Wqkv, Wot);

  dim3 g1(32, 12);
  gemm_qkv<<<g1, 512, 0, stream>>>(Xb, Wqkv, bQ, bK, bV, Qg, Kg, Vpg);
  dim3 g2(64, 8);
  flash_attn<<<g2, 256, 0, stream>>>(Qg, Kg, Vpg, OH);
  dim3 g3(64, 16);
  gemm_o<<<g3, 256, 0, stream>>>(OH, Wot, bO, out);
}

// Round 10
// 255.099 us; speedup vs baseline: 1.0522x; 1.0522x over previous
//
#include <hip/hip_runtime.h>
#include <stdint.h>

// Attention fwd: B=4 T=2048 D=1024 H=16 Dh=64.
// R18 = R16 (measured best 252.4) with ONE delta in flash: l computed on the
//   MFMA pipe via ones-matrix row-sum — lacc[qi] = MFMA(pa[qi], ones, lacc).
//   Removes 64 VALU/tile/wave (l_part adds) + epilogue shfl reduce; adds
//   8 MFMA/tile on the less-busy pipe. lacc C/D layout == o's, so epilogue
//   reads lacc[qi][r] in-lane. Also makes l consistent with truncated-bf16 P
//   used by PV (numerator/denominator same rounding).
// flash was VALUBusy 46 + MfmaUtil 39 ~ 85% combined (co-issue ceiling);
//   only removing VALU work can help. qkv 256^2 line abandoned (R13-R17:
//   race, then un-steerable 128-VGPR spill x3). qkv/gemm_o/prep = R16.

typedef __attribute__((ext_vector_type(8))) short bf16x8;
typedef __attribute__((ext_vector_type(4))) float f32x4;

#define MFMA32 __builtin_amdgcn_mfma_f32_16x16x32_bf16

#if __has_builtin(__builtin_amdgcn_exp2f)
#define EXP2(x) __builtin_amdgcn_exp2f(x)
#else
#define EXP2(x) exp2f(x)   // host pass only
#endif

__device__ __forceinline__ unsigned short f2bf(float f) {
  union { float f; unsigned int u; } v; v.f = f;
  unsigned int r = v.u + 0x7FFFu + ((v.u >> 16) & 1u);  // RNE
  return (unsigned short)(r >> 16);
}

__device__ __forceinline__ void gl_lds16(const void* g, void* l) {
  __builtin_amdgcn_global_load_lds(
      (const __attribute__((address_space(1))) unsigned int*)g,
      (__attribute__((address_space(3))) unsigned int*)l, 16, 0, 0);
}

// truncating pack of two positive fp32 -> one u32 (two bf16)
__device__ __forceinline__ unsigned packbf2(float lo, float hi) {
  union { float f; unsigned u; } a, b; a.f = lo; b.f = hi;
  return __builtin_amdgcn_perm(b.u, a.u, 0x07060302u);
}

// LDS chunk swizzle for K/V tiles (conflict-free for permuted-row b128 reads)
__device__ __forceinline__ int rho(int r) { return (r & 3) | ((r >> 1) & 4); }

// ---------------- merged prep kernel ----------------
__device__ __forceinline__ void conv8(const float* __restrict__ src,
                                      unsigned short* __restrict__ dst, int i) {
  const float4* sp = (const float4*)src;
  float4 a = sp[2 * i], b = sp[2 * i + 1];
  union { unsigned short u[8]; uint4 v; } o;
  o.u[0] = f2bf(a.x); o.u[1] = f2bf(a.y); o.u[2] = f2bf(a.z); o.u[3] = f2bf(a.w);
  o.u[4] = f2bf(b.x); o.u[5] = f2bf(b.y); o.u[6] = f2bf(b.z); o.u[7] = f2bf(b.w);
  ((uint4*)dst)[i] = o.v;
}

__global__ __launch_bounds__(256) void prep_all(
    const float* __restrict__ x, const float* __restrict__ WQ,
    const float* __restrict__ WK, const float* __restrict__ WV,
    const float* __restrict__ WO, unsigned short* __restrict__ Xb,
    unsigned short* __restrict__ Wqkv, unsigned short* __restrict__ Wot) {
  const int bx = blockIdx.x, t = threadIdx.x;
  if (bx < 4096) {
    conv8(x, Xb, bx * 256 + t);
  } else if (bx < 4608) {
    conv8(WQ, Wqkv, (bx - 4096) * 256 + t);
  } else if (bx < 5120) {
    conv8(WK, Wqkv + 1048576, (bx - 4608) * 256 + t);
  } else if (bx < 5632) {
    conv8(WV, Wqkv + 2097152, (bx - 5120) * 256 + t);
  } else {
    // W_O [16][1024][64] fp32 -> Wot [d][h*64+k] bf16
    int tid = (bx - 5632) * 256 + t;
    int h = tid >> 13, rem = tid & 8191;
    int d = rem >> 3, c = rem & 7;
    const float4* sp = (const float4*)(WO + (size_t)h * 65536 + d * 64 + c * 8);
    float4 a = sp[0], e = sp[1];
    union { unsigned short u[8]; uint4 v; } o;
    o.u[0] = f2bf(a.x); o.u[1] = f2bf(a.y); o.u[2] = f2bf(a.z); o.u[3] = f2bf(a.w);
    o.u[4] = f2bf(e.x); o.u[5] = f2bf(e.y); o.u[6] = f2bf(e.z); o.u[7] = f2bf(e.w);
    *(uint4*)(Wot + (size_t)d * 1024 + h * 64 + c * 8) = o.v;
  }
}

// ---------------- QKV projection: 256x192 tile, 8-phase pipelined ----------------
// LDS ushort layout: A0 @0 (256x64), B0 @16384 (192x64), A1 @28672, B1 @45056.
// Swizzle: element (row,k) at row*64 + ((k>>3)^(row&7))*8 + (k&7)  (involution,
// staged via pre-swizzled global source; measured 0 bank conflicts).

template <int MH, int C>
__device__ __forceinline__ void qkv_ds_a(const unsigned short* A, int wm, int quad,
                                         int l15, bf16x8 ar[4][2]) {
#pragma unroll
  for (int ii = 0; ii < 4; ++ii) {
    int ra = wm * 128 + MH * 64 + ii * 16 + l15;
    ar[ii][C] = *(const bf16x8*)(A + ra * 64 + (((C * 4 + quad) ^ (ra & 7)) * 8));
  }
}

template <int C>
__device__ __forceinline__ void qkv_ds_b(const unsigned short* B, int wn, int quad,
                                         int l15, bf16x8 br[3][2]) {
#pragma unroll
  for (int nj = 0; nj < 3; ++nj) {
    int rb = wn * 48 + nj * 16 + l15;
    br[nj][C] = *(const bf16x8*)(B + rb * 64 + (((C * 4 + quad) ^ (rb & 7)) * 8));
  }
}

template <int MH, int C>
__device__ __forceinline__ void qkv_mf(const bf16x8 ar[4][2], const bf16x8 br[3][2],
                                       f32x4 acc[8][3]) {
#pragma unroll
  for (int ii = 0; ii < 4; ++ii)
#pragma unroll
    for (int nj = 0; nj < 3; ++nj)
      acc[MH * 4 + ii][nj] =
          MFMA32(ar[ii][C], br[nj][C], acc[MH * 4 + ii][nj], 0, 0, 0);
}

#define QKV_BAR() __builtin_amdgcn_s_barrier()
#define QKV_LGKM0() asm volatile("s_waitcnt lgkmcnt(0)" ::: "memory")
#define SA_(bb, kt, u) \
  gl_lds16(Xb + (size_t)aoff[u] + (size_t)(kt) * 64, lds + (bb)*28672 + adst[u])
#define SB_(bb, kt, u) \
  gl_lds16(Wqkv + (size_t)boff[u] + (size_t)(kt) * 64, lds + (bb)*28672 + 16384 + bdst[u])

__global__ __launch_bounds__(512, 2) void gemm_qkv(
    const unsigned short* __restrict__ Xb, const unsigned short* __restrict__ Wqkv,
    const float* __restrict__ bQ, const float* __restrict__ bK,
    const float* __restrict__ bV, unsigned short* __restrict__ Qg,
    unsigned short* __restrict__ Kg, unsigned int* __restrict__ Vpg) {
  __shared__ unsigned short lds[57344];  // 112 KB
  const int tid = threadIdx.x, lane = tid & 63, w = tid >> 6;
  const int quad = lane >> 4, l15 = lane & 15;
  const int wm = w >> 2, wn = w & 3;
  const int m0 = blockIdx.x * 256, n0 = blockIdx.y * 192;

  // staging source offsets (inverse-swizzled global address; LDS dest linear)
  int aoff[4], adst[4];
#pragma unroll
  for (int u = 0; u < 4; ++u) {
    int s = u * 512 + tid, row = s >> 3;
    aoff[u] = (m0 + row) * 1024 + (((s & 7) ^ (row & 7)) * 8);
    adst[u] = s * 8;
  }
  int boff[3], bdst[3];
#pragma unroll
  for (int u = 0; u < 3; ++u) {
    int s = u * 512 + tid, row = s >> 3;
    boff[u] = (n0 + row) * 1024 + (((s & 7) ^ (row & 7)) * 8);
    bdst[u] = s * 8;
  }

  const unsigned short* A0 = lds;
  const unsigned short* B0 = lds + 16384;
  const unsigned short* A1 = lds + 28672;
  const unsigned short* B1 = lds + 45056;

  f32x4 acc[8][3];
#pragma unroll
  for (int i = 0; i < 8; ++i)
#pragma unroll
    for (int j = 0; j < 3; ++j) acc[i][j] = (f32x4){0.f, 0.f, 0.f, 0.f};
  bf16x8 ar[4][2], br[3][2];

  // prologue: tile0 full -> buf0 (7 loads); tile1 B -> buf1 (3 loads)
  SA_(0, 0, 0); SA_(0, 0, 1); SA_(0, 0, 2); SA_(0, 0, 3);
  SB_(0, 0, 0); SB_(0, 0, 1); SB_(0, 0, 2);
  SB_(1, 1, 0); SB_(1, 1, 1); SB_(1, 1, 2);
  asm volatile("s_waitcnt vmcnt(3)" ::: "memory");  // tile0 landed; tile1-B in flight
  QKV_BAR();

  // 16 K-tiles of 64; iteration i computes tiles 2i (buf0) and 2i+1 (buf1).
  // Staging map (1 half-tile/phase): ph0/1 A(2i+1)->buf1, ph2/3 B(2i+2)->buf0,
  // ph4/5 A(2i+2)->buf0, ph6/7 B(2i+3)->buf1. Counted waits at end of ph3/ph7.
#pragma unroll 1
  for (int i = 0; i < 8; ++i) {
    const int tn = 2 * i + 2;
    const bool st = (i < 7);
    // ph0: buf0 (mh0,c0)
    qkv_ds_a<0, 0>(A0, wm, quad, l15, ar);
    qkv_ds_b<0>(B0, wn, quad, l15, br);
    SA_(1, 2 * i + 1, 0); SA_(1, 2 * i + 1, 1);
    QKV_BAR(); QKV_LGKM0();
    __builtin_amdgcn_s_setprio(1); qkv_mf<0, 0>(ar, br, acc); __builtin_amdgcn_s_setprio(0);
    QKV_BAR();
    // ph1: buf0 (mh0,c1)
    qkv_ds_a<0, 1>(A0, wm, quad, l15, ar);
    qkv_ds_b<1>(B0, wn, quad, l15, br);
    SA_(1, 2 * i + 1, 2); SA_(1, 2 * i + 1, 3);
    QKV_BAR(); QKV_LGKM0();
    __builtin_amdgcn_s_setprio(1); qkv_mf<0, 1>(ar, br, acc); __builtin_amdgcn_s_setprio(0);
    QKV_BAR();
    // ph2: buf0 (mh1,c0); B(buf0) free (reads done ph1)
    qkv_ds_a<1, 0>(A0, wm, quad, l15, ar);
    if (st) { SB_(0, tn, 0); SB_(0, tn, 1); }
    QKV_BAR(); QKV_LGKM0();
    __builtin_amdgcn_s_setprio(1); qkv_mf<1, 0>(ar, br, acc); __builtin_amdgcn_s_setprio(0);
    QKV_BAR();
    // ph3: buf0 (mh1,c1); counted wait: tile 2i+1 (buf1) must be landed past here
    qkv_ds_a<1, 1>(A0, wm, quad, l15, ar);
    if (st) SB_(0, tn, 2);
    QKV_BAR(); QKV_LGKM0();
    __builtin_amdgcn_s_setprio(1); qkv_mf<1, 1>(ar, br, acc); __builtin_amdgcn_s_setprio(0);
    if (st) asm volatile("s_waitcnt vmcnt(3)" ::: "memory");  // leaves ph2/3 B in flight
    else    asm volatile("s_waitcnt vmcnt(0)" ::: "memory");  // last iter: drain all
    QKV_BAR();
    // ph4: buf1 (mh0,c0); A(buf0) free (reads done ph3)
    qkv_ds_a<0, 0>(A1, wm, quad, l15, ar);
    qkv_ds_b<0>(B1, wn, quad, l15, br);
    if (st) { SA_(0, tn, 0); SA_(0, tn, 1); }
    QKV_BAR(); QKV_LGKM0();
    __builtin_amdgcn_s_setprio(1); qkv_mf<0, 0>(ar, br, acc); __builtin_amdgcn_s_setprio(0);
    QKV_BAR();
    // ph5: buf1 (mh0,c1)
    qkv_ds_a<0, 1>(A1, wm, quad, l15, ar);
    qkv_ds_b<1>(B1, wn, quad, l15, br);
    if (st) { SA_(0, tn, 2); SA_(0, tn, 3); }
    QKV_BAR(); QKV_LGKM0();
    __builtin_amdgcn_s_setprio(1); qkv_mf<0, 1>(ar, br, acc); __builtin_amdgcn_s_setprio(0);
    QKV_BAR();
    // ph6: buf1 (mh1,c0); B(buf1) free (reads done ph5)
    qkv_ds_a<1, 0>(A1, wm, quad, l15, ar);
    if (st) { SB_(1, tn + 1, 0); SB_(1, tn + 1, 1); }
    QKV_BAR(); QKV_LGKM0();
    __builtin_amdgcn_s_setprio(1); qkv_mf<1, 0>(ar, br, acc); __builtin_amdgcn_s_setprio(0);
    QKV_BAR();
    // ph7: buf1 (mh1,c1); counted wait: tile 2i+2 (buf0) landed past here
    qkv_ds_a<1, 1>(A1, wm, quad, l15, ar);
    if (st) SB_(1, tn + 1, 2);
    QKV_BAR(); QKV_LGKM0();
    __builtin_amdgcn_s_setprio(1); qkv_mf<1, 1>(ar, br, acc); __builtin_amdgcn_s_setprio(0);
    asm volatile("s_waitcnt vmcnt(3)" ::: "memory");  // leaves ph6/7 B in flight
    QKV_BAR();
  }

  // epilogue: C[row = m0+wm*128+mi*16+quad*4+r][col = n0+wn*48+nj*16+l15]
#pragma unroll
  for (int nj = 0; nj < 3; ++nj) {
    const int n_abs = n0 + wn * 48 + nj * 16 + l15;  // 0..3071
    const int type = n_abs >> 10;                    // 0=Q 1=K 2=V
    const int n_in = n_abs & 1023;
    const int h = n_in >> 6, kh = n_in & 63;
    const float bv = ((type == 0) ? bQ : (type == 1) ? bK : bV)[n_in];
#pragma unroll
    for (int mi = 0; mi < 8; ++mi) {
      const int mb = m0 + wm * 128 + mi * 16 + quad * 4;
      const int b = mb >> 11, tb = mb & 2047;
      if (type == 2) {
        uint2 pk;
        pk.x = (unsigned)f2bf(acc[mi][nj][0] + bv) |
               ((unsigned)f2bf(acc[mi][nj][1] + bv) << 16);
        pk.y = (unsigned)f2bf(acc[mi][nj][2] + bv) |
               ((unsigned)f2bf(acc[mi][nj][3] + bv) << 16);
        *(uint2*)(Vpg + ((size_t)(b * 16 + h) * 64 + kh) * 1024 + (tb >> 1)) = pk;
      } else {
        unsigned short* dst =
            ((type == 0) ? Qg : Kg) + ((size_t)(b * 16 + h) * 2048 + tb) * 64 + kh;
        // Q pre-scaled by 1/sqrt(Dh) * log2(e) so flash uses exp2 directly
        const float sc = (type == 0) ? 0.18033688011112042f : 1.0f;
        dst[0]   = f2bf((acc[mi][nj][0] + bv) * sc);
        dst[64]  = f2bf((acc[mi][nj][1] + bv) * sc);
        dst[128] = f2bf((acc[mi][nj][2] + bv) * sc);
        dst[192] = f2bf((acc[mi][nj][3] + bv) * sc);
      }
    }
  }
}

#undef SA_
#undef SB_
#undef QKV_BAR
#undef QKV_LGKM0

// ---------------- flash attention (R9 form + setprio + MFMA l-sum) ----------
__device__ __forceinline__ void stage_kv(const unsigned short* __restrict__ Kb,
                                         const unsigned int* __restrict__ Vb,
                                         unsigned short* smem, int tid, int s0, int b) {
#pragma unroll
  for (int u = 0; u < 2; ++u) {
    int s = u * 256 + tid, row = s >> 3, g = (s & 7) ^ rho(row);
    gl_lds16(Kb + (size_t)(s0 + row) * 64 + g * 8, smem + b * 8192 + s * 8);
    gl_lds16(Vb + (size_t)row * 1024 + (s0 >> 1) + g * 4,
             smem + b * 8192 + 4096 + s * 8);
  }
}

// block: 256 q-rows of one (b,h); wave owns 64 q; k-tiles of 64, double-buffered.
// grid (bh=64, qt=8): all q-tiles of one bh on one XCD -> K/V L2-local.
__global__ __launch_bounds__(256, 2) void flash_attn(
    const unsigned short* __restrict__ Qg, const unsigned short* __restrict__ Kg,
    const unsigned int* __restrict__ Vpg, unsigned short* __restrict__ OH) {
  __shared__ unsigned short smem[16384];  // 32KB: [K0 8K][V0 8K][K1 8K][V1 8K]
  const int tid = threadIdx.x, lane = tid & 63, w = tid >> 6;
  const int quad = lane >> 4, l15 = lane & 15;
  const int bh = blockIdx.x, qt = blockIdx.y;

  const unsigned short* Qb = Qg + ((size_t)bh * 2048 + qt * 256) * 64;
  const unsigned short* Kb = Kg + (size_t)bh * 2048 * 64;
  const unsigned int*  Vb = Vpg + (size_t)bh * 64 * 1024;

  // stage Q (256 rows = 32KB, whole smem) — dead before tile 0
#pragma unroll
  for (int u = 0; u < 8; ++u) {
    int s = u * 256 + tid, row = s >> 3;
    gl_lds16(Qb + row * 64 + ((s & 7) ^ (row & 7)) * 8, smem + s * 8);
  }
  __syncthreads();

  bf16x8 qf[4][2];  // B-operand Q frags, hoisted for whole kernel
#pragma unroll
  for (int qi = 0; qi < 4; ++qi) {
    int row = w * 64 + qi * 16 + l15;
#pragma unroll
    for (int c = 0; c < 2; ++c)
      qf[qi][c] = *(const bf16x8*)(smem + row * 64 + (((c * 4 + quad) ^ (row & 7)) * 8));
  }
  __syncthreads();  // all waves done reading Q; safe to overwrite with K0/V0

  stage_kv(Kb, Vb, smem, tid, 0, 0);

  // ones matrix (bf16 1.0 = 0x3F80) as PV B-operand for l row-sums
  union { uint4 q; bf16x8 v; } onesu;
  onesu.q = make_uint4(0x3F803F80u, 0x3F803F80u, 0x3F803F80u, 0x3F803F80u);
  const bf16x8 ones = onesu.v;

  f32x4 o[4][4];
  f32x4 lacc[4];  // l row-sums, same C/D layout as o: row 4*quad+r, col l15
#pragma unroll
  for (int qi = 0; qi < 4; ++qi) {
    lacc[qi] = (f32x4){0.f, 0.f, 0.f, 0.f};
#pragma unroll
    for (int nj = 0; nj < 4; ++nj) o[qi][nj] = (f32x4){0.f, 0.f, 0.f, 0.f};
  }

  for (int t = 0; t < 32; ++t) {
    __syncthreads();  // drains tile-t staging
    if (t < 31) stage_kv(Kb, Vb, smem, tid, (t + 1) * 64, (t + 1) & 1);
    const unsigned short* Kd = smem + (t & 1) * 8192;
    const unsigned short* Vd = Kd + 4096;

#pragma unroll
    for (int blk = 0; blk < 2; ++blk) {
      // V B-frags: Vt[dh = nj*16+l15][s = blk*32 + quad*8 .. +7] — one b128 each
      bf16x8 vb[4];
#pragma unroll
      for (int nj = 0; nj < 4; ++nj) {
        int vrow = nj * 16 + l15;
        vb[nj] = *(const bf16x8*)(Vd + vrow * 64 + (((blk * 4 + quad) ^ rho(vrow)) * 8));
      }
      union { unsigned u[4]; bf16x8 v; } pa[4];
#pragma unroll
      for (int v = 0; v < 2; ++v) {
        // permuted K rows: C/D row m maps to s = blk*32 + 8*quad + 4*v + reg
        int krow = blk * 32 + 8 * (l15 >> 2) + 4 * v + (l15 & 3);
        const unsigned short* kr = Kd + krow * 64;
        bf16x8 ka0 = *(const bf16x8*)(kr + ((quad ^ rho(krow)) * 8));
        bf16x8 ka1 = *(const bf16x8*)(kr + (((4 + quad) ^ rho(krow)) * 8));
#pragma unroll
        for (int qi = 0; qi < 4; ++qi) {
          f32x4 S = (f32x4){0.f, 0.f, 0.f, 0.f};
          S = MFMA32(ka0, qf[qi][0], S, 0, 0, 0);
          S = MFMA32(ka1, qf[qi][1], S, 0, 0, 0);
          float e0 = EXP2(S[0]), e1 = EXP2(S[1]), e2 = EXP2(S[2]), e3 = EXP2(S[3]);
          pa[qi].u[2 * v] = packbf2(e0, e1);
          pa[qi].u[2 * v + 1] = packbf2(e2, e3);
        }
      }
      // PV + l row-sums on the MFMA pipe (T5 setprio around cluster)
      __builtin_amdgcn_s_setprio(1);
#pragma unroll
      for (int qi = 0; qi < 4; ++qi) {
        lacc[qi] = MFMA32(pa[qi].v, ones, lacc[qi], 0, 0, 0);
#pragma unroll
        for (int nj = 0; nj < 4; ++nj)
          o[qi][nj] = MFMA32(pa[qi].v, vb[nj], o[qi][nj], 0, 0, 0);
      }
      __builtin_amdgcn_s_setprio(0);
    }
  }

  // normalize + store: lacc[qi][r] is the row-sum for trow's own lane — no shfl
  const int b = bh >> 4, h = bh & 15;
#pragma unroll
  for (int qi = 0; qi < 4; ++qi) {
#pragma unroll
    for (int r = 0; r < 4; ++r) {
      float lr = 1.0f / lacc[qi][r];
      int trow = qt * 256 + w * 64 + qi * 16 + 4 * quad + r;
#pragma unroll
      for (int nj = 0; nj < 4; ++nj) {
        int col = h * 64 + nj * 16 + l15;
        OH[((size_t)b * 2048 + trow) * 1024 + col] = f2bf(o[qi][nj][r] * lr);
      }
    }
  }
}

// ---------------- output projection (128x64 tile, R9 form) ----------------
__global__ __launch_bounds__(256) void gemm_o(
    const unsigned short* __restrict__ OHm, const unsigned short* __restrict__ Wot,
    const float* __restrict__ bO, float* __restrict__ Out) {
  __shared__ unsigned short As[128 * 64];  // 16KB
  __shared__ unsigned short Bs[64 * 64];   // 8KB
  const int tid = threadIdx.x, lane = tid & 63, w = tid >> 6;
  const int quad = lane >> 4, l15 = lane & 15;
  const int wm = w & 1, wn = w >> 1;
  const int m0 = blockIdx.x * 128, n0 = blockIdx.y * 64;
  f32x4 acc[4][2];
#pragma unroll
  for (int i = 0; i < 4; ++i)
#pragma unroll
    for (int j = 0; j < 2; ++j) acc[i][j] = (f32x4){0.f, 0.f, 0.f, 0.f};

  for (int k0 = 0; k0 < 1024; k0 += 64) {
    __syncthreads();
#pragma unroll
    for (int u = 0; u < 4; ++u) {
      int s = u * 256 + tid, row = s >> 3;
      int cl = ((s & 7) ^ (row & 7)) * 8;
      gl_lds16(OHm + (size_t)(m0 + row) * 1024 + k0 + cl, As + s * 8);
    }
#pragma unroll
    for (int u = 0; u < 2; ++u) {
      int s = u * 256 + tid, row = s >> 3;
      int cl = ((s & 7) ^ (row & 7)) * 8;
      gl_lds16(Wot + (size_t)(n0 + row) * 1024 + k0 + cl, Bs + s * 8);
    }
    __syncthreads();
    bf16x8 af[4][2], bfr[2][2];
#pragma unroll
    for (int i = 0; i < 4; ++i) {
      int ra = wm * 64 + i * 16 + l15;
#pragma unroll
      for (int c = 0; c < 2; ++c)
        af[i][c] = *(const bf16x8*)(As + ra * 64 + (((c * 4 + quad) ^ (ra & 7)) * 8));
    }
#pragma unroll
    for (int j = 0; j < 2; ++j) {
      int rb = wn * 32 + j * 16 + l15;
#pragma unroll
      for (int c = 0; c < 2; ++c)
        bfr[j][c] = *(const bf16x8*)(Bs + rb * 64 + (((c * 4 + quad) ^ (rb & 7)) * 8));
    }
#pragma unroll
    for (int mi = 0; mi < 4; ++mi)
#pragma unroll
      for (int nj = 0; nj < 2; ++nj) {
        acc[mi][nj] = MFMA32(af[mi][0], bfr[nj][0], acc[mi][nj], 0, 0, 0);
        acc[mi][nj] = MFMA32(af[mi][1], bfr[nj][1], acc[mi][nj], 0, 0, 0);
      }
  }

#pragma unroll
  for (int nj = 0; nj < 2; ++nj) {
    const int n = n0 + wn * 32 + nj * 16 + l15;
    const float bv = bO[n];
#pragma unroll
    for (int mi = 0; mi < 4; ++mi) {
      const int mb = m0 + wm * 64 + mi * 16 + quad * 4;
#pragma unroll
      for (int r = 0; r < 4; ++r)
        Out[(size_t)(mb + r) * 1024 + n] = acc[mi][nj][r] + bv;
    }
  }
}

// ---------------- launch ----------------
extern "C" void kernel_launch(void* const* d_in, const int* in_sizes, int n_in,
                              void* d_out, int out_size, void* d_ws, size_t ws_size,
                              hipStream_t stream) {
  const float* x  = (const float*)d_in[0];
  const float* WQ = (const float*)d_in[1];
  const float* bQ = (const float*)d_in[2];
  const float* WK = (const float*)d_in[3];
  const float* bK = (const float*)d_in[4];
  const float* WV = (const float*)d_in[5];
  const float* bV = (const float*)d_in[6];
  const float* WO = (const float*)d_in[7];
  const float* bO = (const float*)d_in[8];
  float* out = (float*)d_out;

  char* ws = (char*)d_ws;
  unsigned short* Xb   = (unsigned short*)(ws);                // 16 MB
  unsigned short* OH   = (unsigned short*)(ws);                // alias (Xb dead)
  unsigned short* Wqkv = (unsigned short*)(ws + 16777216);     // 6 MB
  unsigned short* Wot  = (unsigned short*)(ws + 23068672);     // 2 MB
  unsigned short* Qg   = (unsigned short*)(ws + 25165824);     // 16 MB
  unsigned short* Kg   = (unsigned short*)(ws + 41943040);     // 16 MB
  unsigned int*   Vpg  = (unsigned int*)  (ws + 58720256);     // 16 MB

  prep_all<<<6144, 256, 0, stream>>>(x, WQ, WK, WV, WO, Xb, Wqkv, Wot);

  dim3 g1(32, 16);
  gemm_qkv<<<g1, 512, 0, stream>>>(Xb, Wqkv, bQ, bK, bV, Qg, Kg, Vpg);
  dim3 g2(64, 8);
  flash_attn<<<g2, 256, 0, stream>>>(Qg, Kg, Vpg, OH);
  dim3 g3(64, 16);
  gemm_o<<<g3, 256, 0, stream>>>(OH, Wot, bO, out);
}

// Round 11
// 252.281 us; speedup vs baseline: 1.0640x; 1.0112x over previous
//
#include <hip/hip_runtime.h>
#include <stdint.h>

// Attention fwd: B=4 T=2048 D=1024 H=16 Dh=64.
// R19 = R18 (flash MFMA-l-sum verified: 71.2us, VALU 46->43, absmax improved)
//   with ONE delta: gemm_o retiled 128x64/2-barrier -> 256x128 8-phase,
//   an exact clone of the verified qkv template (B reg-cache contract,
//   counted vmcnt(2) at ph3/ph7 — ledger: loads/tile A=4 B=2; at ph3 queue
//   [B1:2][A1:4][B0:2] drain 6 leave 2). Grid (32,8)=256 blocks = 1.0
//   rounds; ~4MB/XCD natural L2 working set; A re-reads halve (x16->x8).
//   acc[8][2]=64 VGPR < qkv's 96 -> spill risk low.
// R18 discovery: qkv 256x192 spills ~27MB (VGPR 104 vs ~152 live) — known,
//   allocator un-steerable (R14-R17). prep+gemm_o+gaps ~= 112us unaccounted;
//   gemm_o (8 MFMA/wave-period, ~384MB L2 traffic) is the suspect.

typedef __attribute__((ext_vector_type(8))) short bf16x8;
typedef __attribute__((ext_vector_type(4))) float f32x4;

#define MFMA32 __builtin_amdgcn_mfma_f32_16x16x32_bf16

#if __has_builtin(__builtin_amdgcn_exp2f)
#define EXP2(x) __builtin_amdgcn_exp2f(x)
#else
#define EXP2(x) exp2f(x)   // host pass only
#endif

__device__ __forceinline__ unsigned short f2bf(float f) {
  union { float f; unsigned int u; } v; v.f = f;
  unsigned int r = v.u + 0x7FFFu + ((v.u >> 16) & 1u);  // RNE
  return (unsigned short)(r >> 16);
}

__device__ __forceinline__ void gl_lds16(const void* g, void* l) {
  __builtin_amdgcn_global_load_lds(
      (const __attribute__((address_space(1))) unsigned int*)g,
      (__attribute__((address_space(3))) unsigned int*)l, 16, 0, 0);
}

// truncating pack of two positive fp32 -> one u32 (two bf16)
__device__ __forceinline__ unsigned packbf2(float lo, float hi) {
  union { float f; unsigned u; } a, b; a.f = lo; b.f = hi;
  return __builtin_amdgcn_perm(b.u, a.u, 0x07060302u);
}

// LDS chunk swizzle for K/V tiles (conflict-free for permuted-row b128 reads)
__device__ __forceinline__ int rho(int r) { return (r & 3) | ((r >> 1) & 4); }

// ---------------- merged prep kernel ----------------
__device__ __forceinline__ void conv8(const float* __restrict__ src,
                                      unsigned short* __restrict__ dst, int i) {
  const float4* sp = (const float4*)src;
  float4 a = sp[2 * i], b = sp[2 * i + 1];
  union { unsigned short u[8]; uint4 v; } o;
  o.u[0] = f2bf(a.x); o.u[1] = f2bf(a.y); o.u[2] = f2bf(a.z); o.u[3] = f2bf(a.w);
  o.u[4] = f2bf(b.x); o.u[5] = f2bf(b.y); o.u[6] = f2bf(b.z); o.u[7] = f2bf(b.w);
  ((uint4*)dst)[i] = o.v;
}

__global__ __launch_bounds__(256) void prep_all(
    const float* __restrict__ x, const float* __restrict__ WQ,
    const float* __restrict__ WK, const float* __restrict__ WV,
    const float* __restrict__ WO, unsigned short* __restrict__ Xb,
    unsigned short* __restrict__ Wqkv, unsigned short* __restrict__ Wot) {
  const int bx = blockIdx.x, t = threadIdx.x;
  if (bx < 4096) {
    conv8(x, Xb, bx * 256 + t);
  } else if (bx < 4608) {
    conv8(WQ, Wqkv, (bx - 4096) * 256 + t);
  } else if (bx < 5120) {
    conv8(WK, Wqkv + 1048576, (bx - 4608) * 256 + t);
  } else if (bx < 5632) {
    conv8(WV, Wqkv + 2097152, (bx - 5120) * 256 + t);
  } else {
    // W_O [16][1024][64] fp32 -> Wot [d][h*64+k] bf16
    int tid = (bx - 5632) * 256 + t;
    int h = tid >> 13, rem = tid & 8191;
    int d = rem >> 3, c = rem & 7;
    const float4* sp = (const float4*)(WO + (size_t)h * 65536 + d * 64 + c * 8);
    float4 a = sp[0], e = sp[1];
    union { unsigned short u[8]; uint4 v; } o;
    o.u[0] = f2bf(a.x); o.u[1] = f2bf(a.y); o.u[2] = f2bf(a.z); o.u[3] = f2bf(a.w);
    o.u[4] = f2bf(e.x); o.u[5] = f2bf(e.y); o.u[6] = f2bf(e.z); o.u[7] = f2bf(e.w);
    *(uint4*)(Wot + (size_t)d * 1024 + h * 64 + c * 8) = o.v;
  }
}

// ---------------- QKV projection: 256x192 tile, 8-phase pipelined ----------------
// LDS ushort layout: A0 @0 (256x64), B0 @16384 (192x64), A1 @28672, B1 @45056.
// Swizzle: element (row,k) at row*64 + ((k>>3)^(row&7))*8 + (k&7)  (involution,
// staged via pre-swizzled global source; measured 0 bank conflicts).

template <int MH, int C>
__device__ __forceinline__ void qkv_ds_a(const unsigned short* A, int wm, int quad,
                                         int l15, bf16x8 ar[4][2]) {
#pragma unroll
  for (int ii = 0; ii < 4; ++ii) {
    int ra = wm * 128 + MH * 64 + ii * 16 + l15;
    ar[ii][C] = *(const bf16x8*)(A + ra * 64 + (((C * 4 + quad) ^ (ra & 7)) * 8));
  }
}

template <int C>
__device__ __forceinline__ void qkv_ds_b(const unsigned short* B, int wn, int quad,
                                         int l15, bf16x8 br[3][2]) {
#pragma unroll
  for (int nj = 0; nj < 3; ++nj) {
    int rb = wn * 48 + nj * 16 + l15;
    br[nj][C] = *(const bf16x8*)(B + rb * 64 + (((C * 4 + quad) ^ (rb & 7)) * 8));
  }
}

template <int MH, int C>
__device__ __forceinline__ void qkv_mf(const bf16x8 ar[4][2], const bf16x8 br[3][2],
                                       f32x4 acc[8][3]) {
#pragma unroll
  for (int ii = 0; ii < 4; ++ii)
#pragma unroll
    for (int nj = 0; nj < 3; ++nj)
      acc[MH * 4 + ii][nj] =
          MFMA32(ar[ii][C], br[nj][C], acc[MH * 4 + ii][nj], 0, 0, 0);
}

#define QKV_BAR() __builtin_amdgcn_s_barrier()
#define QKV_LGKM0() asm volatile("s_waitcnt lgkmcnt(0)" ::: "memory")
#define SA_(bb, kt, u) \
  gl_lds16(Xb + (size_t)aoff[u] + (size_t)(kt) * 64, lds + (bb)*28672 + adst[u])
#define SB_(bb, kt, u) \
  gl_lds16(Wqkv + (size_t)boff[u] + (size_t)(kt) * 64, lds + (bb)*28672 + 16384 + bdst[u])

__global__ __launch_bounds__(512, 2) void gemm_qkv(
    const unsigned short* __restrict__ Xb, const unsigned short* __restrict__ Wqkv,
    const float* __restrict__ bQ, const float* __restrict__ bK,
    const float* __restrict__ bV, unsigned short* __restrict__ Qg,
    unsigned short* __restrict__ Kg, unsigned int* __restrict__ Vpg) {
  __shared__ unsigned short lds[57344];  // 112 KB
  const int tid = threadIdx.x, lane = tid & 63, w = tid >> 6;
  const int quad = lane >> 4, l15 = lane & 15;
  const int wm = w >> 2, wn = w & 3;
  const int m0 = blockIdx.x * 256, n0 = blockIdx.y * 192;

  // staging source offsets (inverse-swizzled global address; LDS dest linear)
  int aoff[4], adst[4];
#pragma unroll
  for (int u = 0; u < 4; ++u) {
    int s = u * 512 + tid, row = s >> 3;
    aoff[u] = (m0 + row) * 1024 + (((s & 7) ^ (row & 7)) * 8);
    adst[u] = s * 8;
  }
  int boff[3], bdst[3];
#pragma unroll
  for (int u = 0; u < 3; ++u) {
    int s = u * 512 + tid, row = s >> 3;
    boff[u] = (n0 + row) * 1024 + (((s & 7) ^ (row & 7)) * 8);
    bdst[u] = s * 8;
  }

  const unsigned short* A0 = lds;
  const unsigned short* B0 = lds + 16384;
  const unsigned short* A1 = lds + 28672;
  const unsigned short* B1 = lds + 45056;

  f32x4 acc[8][3];
#pragma unroll
  for (int i = 0; i < 8; ++i)
#pragma unroll
    for (int j = 0; j < 3; ++j) acc[i][j] = (f32x4){0.f, 0.f, 0.f, 0.f};
  bf16x8 ar[4][2], br[3][2];

  // prologue: tile0 full -> buf0 (7 loads); tile1 B -> buf1 (3 loads)
  SA_(0, 0, 0); SA_(0, 0, 1); SA_(0, 0, 2); SA_(0, 0, 3);
  SB_(0, 0, 0); SB_(0, 0, 1); SB_(0, 0, 2);
  SB_(1, 1, 0); SB_(1, 1, 1); SB_(1, 1, 2);
  asm volatile("s_waitcnt vmcnt(3)" ::: "memory");  // tile0 landed; tile1-B in flight
  QKV_BAR();

  // 16 K-tiles of 64; iteration i computes tiles 2i (buf0) and 2i+1 (buf1).
  // Staging map (1 half-tile/phase): ph0/1 A(2i+1)->buf1, ph2/3 B(2i+2)->buf0,
  // ph4/5 A(2i+2)->buf0, ph6/7 B(2i+3)->buf1. Counted waits at end of ph3/ph7.
#pragma unroll 1
  for (int i = 0; i < 8; ++i) {
    const int tn = 2 * i + 2;
    const bool st = (i < 7);
    // ph0: buf0 (mh0,c0)
    qkv_ds_a<0, 0>(A0, wm, quad, l15, ar);
    qkv_ds_b<0>(B0, wn, quad, l15, br);
    SA_(1, 2 * i + 1, 0); SA_(1, 2 * i + 1, 1);
    QKV_BAR(); QKV_LGKM0();
    __builtin_amdgcn_s_setprio(1); qkv_mf<0, 0>(ar, br, acc); __builtin_amdgcn_s_setprio(0);
    QKV_BAR();
    // ph1: buf0 (mh0,c1)
    qkv_ds_a<0, 1>(A0, wm, quad, l15, ar);
    qkv_ds_b<1>(B0, wn, quad, l15, br);
    SA_(1, 2 * i + 1, 2); SA_(1, 2 * i + 1, 3);
    QKV_BAR(); QKV_LGKM0();
    __builtin_amdgcn_s_setprio(1); qkv_mf<0, 1>(ar, br, acc); __builtin_amdgcn_s_setprio(0);
    QKV_BAR();
    // ph2: buf0 (mh1,c0); B(buf0) free (reads done ph1)
    qkv_ds_a<1, 0>(A0, wm, quad, l15, ar);
    if (st) { SB_(0, tn, 0); SB_(0, tn, 1); }
    QKV_BAR(); QKV_LGKM0();
    __builtin_amdgcn_s_setprio(1); qkv_mf<1, 0>(ar, br, acc); __builtin_amdgcn_s_setprio(0);
    QKV_BAR();
    // ph3: buf0 (mh1,c1); counted wait: tile 2i+1 (buf1) must be landed past here
    qkv_ds_a<1, 1>(A0, wm, quad, l15, ar);
    if (st) SB_(0, tn, 2);
    QKV_BAR(); QKV_LGKM0();
    __builtin_amdgcn_s_setprio(1); qkv_mf<1, 1>(ar, br, acc); __builtin_amdgcn_s_setprio(0);
    if (st) asm volatile("s_waitcnt vmcnt(3)" ::: "memory");  // leaves ph2/3 B in flight
    else    asm volatile("s_waitcnt vmcnt(0)" ::: "memory");  // last iter: drain all
    QKV_BAR();
    // ph4: buf1 (mh0,c0); A(buf0) free (reads done ph3)
    qkv_ds_a<0, 0>(A1, wm, quad, l15, ar);
    qkv_ds_b<0>(B1, wn, quad, l15, br);
    if (st) { SA_(0, tn, 0); SA_(0, tn, 1); }
    QKV_BAR(); QKV_LGKM0();
    __builtin_amdgcn_s_setprio(1); qkv_mf<0, 0>(ar, br, acc); __builtin_amdgcn_s_setprio(0);
    QKV_BAR();
    // ph5: buf1 (mh0,c1)
    qkv_ds_a<0, 1>(A1, wm, quad, l15, ar);
    qkv_ds_b<1>(B1, wn, quad, l15, br);
    if (st) { SA_(0, tn, 2); SA_(0, tn, 3); }
    QKV_BAR(); QKV_LGKM0();
    __builtin_amdgcn_s_setprio(1); qkv_mf<0, 1>(ar, br, acc); __builtin_amdgcn_s_setprio(0);
    QKV_BAR();
    // ph6: buf1 (mh1,c0); B(buf1) free (reads done ph5)
    qkv_ds_a<1, 0>(A1, wm, quad, l15, ar);
    if (st) { SB_(1, tn + 1, 0); SB_(1, tn + 1, 1); }
    QKV_BAR(); QKV_LGKM0();
    __builtin_amdgcn_s_setprio(1); qkv_mf<1, 0>(ar, br, acc); __builtin_amdgcn_s_setprio(0);
    QKV_BAR();
    // ph7: buf1 (mh1,c1); counted wait: tile 2i+2 (buf0) landed past here
    qkv_ds_a<1, 1>(A1, wm, quad, l15, ar);
    if (st) SB_(1, tn + 1, 2);
    QKV_BAR(); QKV_LGKM0();
    __builtin_amdgcn_s_setprio(1); qkv_mf<1, 1>(ar, br, acc); __builtin_amdgcn_s_setprio(0);
    asm volatile("s_waitcnt vmcnt(3)" ::: "memory");  // leaves ph6/7 B in flight
    QKV_BAR();
  }

  // epilogue: C[row = m0+wm*128+mi*16+quad*4+r][col = n0+wn*48+nj*16+l15]
#pragma unroll
  for (int nj = 0; nj < 3; ++nj) {
    const int n_abs = n0 + wn * 48 + nj * 16 + l15;  // 0..3071
    const int type = n_abs >> 10;                    // 0=Q 1=K 2=V
    const int n_in = n_abs & 1023;
    const int h = n_in >> 6, kh = n_in & 63;
    const float bv = ((type == 0) ? bQ : (type == 1) ? bK : bV)[n_in];
#pragma unroll
    for (int mi = 0; mi < 8; ++mi) {
      const int mb = m0 + wm * 128 + mi * 16 + quad * 4;
      const int b = mb >> 11, tb = mb & 2047;
      if (type == 2) {
        uint2 pk;
        pk.x = (unsigned)f2bf(acc[mi][nj][0] + bv) |
               ((unsigned)f2bf(acc[mi][nj][1] + bv) << 16);
        pk.y = (unsigned)f2bf(acc[mi][nj][2] + bv) |
               ((unsigned)f2bf(acc[mi][nj][3] + bv) << 16);
        *(uint2*)(Vpg + ((size_t)(b * 16 + h) * 64 + kh) * 1024 + (tb >> 1)) = pk;
      } else {
        unsigned short* dst =
            ((type == 0) ? Qg : Kg) + ((size_t)(b * 16 + h) * 2048 + tb) * 64 + kh;
        // Q pre-scaled by 1/sqrt(Dh) * log2(e) so flash uses exp2 directly
        const float sc = (type == 0) ? 0.18033688011112042f : 1.0f;
        dst[0]   = f2bf((acc[mi][nj][0] + bv) * sc);
        dst[64]  = f2bf((acc[mi][nj][1] + bv) * sc);
        dst[128] = f2bf((acc[mi][nj][2] + bv) * sc);
        dst[192] = f2bf((acc[mi][nj][3] + bv) * sc);
      }
    }
  }
}

#undef SA_
#undef SB_

// ---------------- flash attention (R9 form + setprio + MFMA l-sum) ----------
__device__ __forceinline__ void stage_kv(const unsigned short* __restrict__ Kb,
                                         const unsigned int* __restrict__ Vb,
                                         unsigned short* smem, int tid, int s0, int b) {
#pragma unroll
  for (int u = 0; u < 2; ++u) {
    int s = u * 256 + tid, row = s >> 3, g = (s & 7) ^ rho(row);
    gl_lds16(Kb + (size_t)(s0 + row) * 64 + g * 8, smem + b * 8192 + s * 8);
    gl_lds16(Vb + (size_t)row * 1024 + (s0 >> 1) + g * 4,
             smem + b * 8192 + 4096 + s * 8);
  }
}

// block: 256 q-rows of one (b,h); wave owns 64 q; k-tiles of 64, double-buffered.
// grid (bh=64, qt=8): all q-tiles of one bh on one XCD -> K/V L2-local.
__global__ __launch_bounds__(256, 2) void flash_attn(
    const unsigned short* __restrict__ Qg, const unsigned short* __restrict__ Kg,
    const unsigned int* __restrict__ Vpg, unsigned short* __restrict__ OH) {
  __shared__ unsigned short smem[16384];  // 32KB: [K0 8K][V0 8K][K1 8K][V1 8K]
  const int tid = threadIdx.x, lane = tid & 63, w = tid >> 6;
  const int quad = lane >> 4, l15 = lane & 15;
  const int bh = blockIdx.x, qt = blockIdx.y;

  const unsigned short* Qb = Qg + ((size_t)bh * 2048 + qt * 256) * 64;
  const unsigned short* Kb = Kg + (size_t)bh * 2048 * 64;
  const unsigned int*  Vb = Vpg + (size_t)bh * 64 * 1024;

  // stage Q (256 rows = 32KB, whole smem) — dead before tile 0
#pragma unroll
  for (int u = 0; u < 8; ++u) {
    int s = u * 256 + tid, row = s >> 3;
    gl_lds16(Qb + row * 64 + ((s & 7) ^ (row & 7)) * 8, smem + s * 8);
  }
  __syncthreads();

  bf16x8 qf[4][2];  // B-operand Q frags, hoisted for whole kernel
#pragma unroll
  for (int qi = 0; qi < 4; ++qi) {
    int row = w * 64 + qi * 16 + l15;
#pragma unroll
    for (int c = 0; c < 2; ++c)
      qf[qi][c] = *(const bf16x8*)(smem + row * 64 + (((c * 4 + quad) ^ (row & 7)) * 8));
  }
  __syncthreads();  // all waves done reading Q; safe to overwrite with K0/V0

  stage_kv(Kb, Vb, smem, tid, 0, 0);

  // ones matrix (bf16 1.0 = 0x3F80) as PV B-operand for l row-sums
  union { uint4 q; bf16x8 v; } onesu;
  onesu.q = make_uint4(0x3F803F80u, 0x3F803F80u, 0x3F803F80u, 0x3F803F80u);
  const bf16x8 ones = onesu.v;

  f32x4 o[4][4];
  f32x4 lacc[4];  // l row-sums, same C/D layout as o: row 4*quad+r, col l15
#pragma unroll
  for (int qi = 0; qi < 4; ++qi) {
    lacc[qi] = (f32x4){0.f, 0.f, 0.f, 0.f};
#pragma unroll
    for (int nj = 0; nj < 4; ++nj) o[qi][nj] = (f32x4){0.f, 0.f, 0.f, 0.f};
  }

  for (int t = 0; t < 32; ++t) {
    __syncthreads();  // drains tile-t staging
    if (t < 31) stage_kv(Kb, Vb, smem, tid, (t + 1) * 64, (t + 1) & 1);
    const unsigned short* Kd = smem + (t & 1) * 8192;
    const unsigned short* Vd = Kd + 4096;

#pragma unroll
    for (int blk = 0; blk < 2; ++blk) {
      // V B-frags: Vt[dh = nj*16+l15][s = blk*32 + quad*8 .. +7] — one b128 each
      bf16x8 vb[4];
#pragma unroll
      for (int nj = 0; nj < 4; ++nj) {
        int vrow = nj * 16 + l15;
        vb[nj] = *(const bf16x8*)(Vd + vrow * 64 + (((blk * 4 + quad) ^ rho(vrow)) * 8));
      }
      union { unsigned u[4]; bf16x8 v; } pa[4];
#pragma unroll
      for (int v = 0; v < 2; ++v) {
        // permuted K rows: C/D row m maps to s = blk*32 + 8*quad + 4*v + reg
        int krow = blk * 32 + 8 * (l15 >> 2) + 4 * v + (l15 & 3);
        const unsigned short* kr = Kd + krow * 64;
        bf16x8 ka0 = *(const bf16x8*)(kr + ((quad ^ rho(krow)) * 8));
        bf16x8 ka1 = *(const bf16x8*)(kr + (((4 + quad) ^ rho(krow)) * 8));
#pragma unroll
        for (int qi = 0; qi < 4; ++qi) {
          f32x4 S = (f32x4){0.f, 0.f, 0.f, 0.f};
          S = MFMA32(ka0, qf[qi][0], S, 0, 0, 0);
          S = MFMA32(ka1, qf[qi][1], S, 0, 0, 0);
          float e0 = EXP2(S[0]), e1 = EXP2(S[1]), e2 = EXP2(S[2]), e3 = EXP2(S[3]);
          pa[qi].u[2 * v] = packbf2(e0, e1);
          pa[qi].u[2 * v + 1] = packbf2(e2, e3);
        }
      }
      // PV + l row-sums on the MFMA pipe (T5 setprio around cluster)
      __builtin_amdgcn_s_setprio(1);
#pragma unroll
      for (int qi = 0; qi < 4; ++qi) {
        lacc[qi] = MFMA32(pa[qi].v, ones, lacc[qi], 0, 0, 0);
#pragma unroll
        for (int nj = 0; nj < 4; ++nj)
          o[qi][nj] = MFMA32(pa[qi].v, vb[nj], o[qi][nj], 0, 0, 0);
      }
      __builtin_amdgcn_s_setprio(0);
    }
  }

  // normalize + store: lacc[qi][r] is the row-sum for trow's own lane — no shfl
  const int b = bh >> 4, h = bh & 15;
#pragma unroll
  for (int qi = 0; qi < 4; ++qi) {
#pragma unroll
    for (int r = 0; r < 4; ++r) {
      float lr = 1.0f / lacc[qi][r];
      int trow = qt * 256 + w * 64 + qi * 16 + 4 * quad + r;
#pragma unroll
      for (int nj = 0; nj < 4; ++nj) {
        int col = h * 64 + nj * 16 + l15;
        OH[((size_t)b * 2048 + trow) * 1024 + col] = f2bf(o[qi][nj][r] * lr);
      }
    }
  }
}

// ---------------- output projection: 256x128 tile, 8-phase pipelined ---------
// Clone of the qkv template with BN=128: A 256x64 (32KB), B 128x64 (16KB),
// double-buffered = 96KB LDS. Loads/tile: A=4, B=2. Counted vmcnt(2) at
// ph3/ph7 (ledger: ph3 queue [B1:2][A1:4][B0:2] -> drain 6, leave 2).
// 8 waves 2Mx4N, per-wave 128x32, acc[8][2]. Grid (32,8)=256 = 1 block/CU.

template <int C>
__device__ __forceinline__ void go_ds_b(const unsigned short* B, int wn, int quad,
                                        int l15, bf16x8 br[2][2]) {
#pragma unroll
  for (int nj = 0; nj < 2; ++nj) {
    int rb = wn * 32 + nj * 16 + l15;
    br[nj][C] = *(const bf16x8*)(B + rb * 64 + (((C * 4 + quad) ^ (rb & 7)) * 8));
  }
}

template <int MH, int C>
__device__ __forceinline__ void go_mf(const bf16x8 ar[4][2], const bf16x8 br[2][2],
                                      f32x4 acc[8][2]) {
#pragma unroll
  for (int ii = 0; ii < 4; ++ii)
#pragma unroll
    for (int nj = 0; nj < 2; ++nj)
      acc[MH * 4 + ii][nj] =
          MFMA32(ar[ii][C], br[nj][C], acc[MH * 4 + ii][nj], 0, 0, 0);
}

#define SA_(bb, kt, u) \
  gl_lds16(OHm + (size_t)aoff[u] + (size_t)(kt) * 64, lds + (bb)*24576 + adst[u])
#define SB_(bb, kt, u) \
  gl_lds16(Wot + (size_t)boff[u] + (size_t)(kt) * 64, lds + (bb)*24576 + 16384 + bdst[u])

__global__ __launch_bounds__(512, 2) void gemm_o(
    const unsigned short* __restrict__ OHm, const unsigned short* __restrict__ Wot,
    const float* __restrict__ bO, float* __restrict__ Out) {
  __shared__ unsigned short lds[49152];  // 96 KB
  const int tid = threadIdx.x, lane = tid & 63, w = tid >> 6;
  const int quad = lane >> 4, l15 = lane & 15;
  const int wm = w >> 2, wn = w & 3;
  const int m0 = blockIdx.x * 256, n0 = blockIdx.y * 128;

  int aoff[4], adst[4];
#pragma unroll
  for (int u = 0; u < 4; ++u) {
    int s = u * 512 + tid, row = s >> 3;
    aoff[u] = (m0 + row) * 1024 + (((s & 7) ^ (row & 7)) * 8);
    adst[u] = s * 8;
  }
  int boff[2], bdst[2];
#pragma unroll
  for (int u = 0; u < 2; ++u) {
    int s = u * 512 + tid, row = s >> 3;
    boff[u] = (n0 + row) * 1024 + (((s & 7) ^ (row & 7)) * 8);
    bdst[u] = s * 8;
  }

  const unsigned short* A0 = lds;
  const unsigned short* B0 = lds + 16384;
  const unsigned short* A1 = lds + 24576;
  const unsigned short* B1 = lds + 40960;

  f32x4 acc[8][2];
#pragma unroll
  for (int i = 0; i < 8; ++i)
#pragma unroll
    for (int j = 0; j < 2; ++j) acc[i][j] = (f32x4){0.f, 0.f, 0.f, 0.f};
  bf16x8 ar[4][2], br[2][2];

  // prologue: tile0 full -> buf0 (6 loads); tile1 B -> buf1 (2 loads)
  SA_(0, 0, 0); SA_(0, 0, 1); SA_(0, 0, 2); SA_(0, 0, 3);
  SB_(0, 0, 0); SB_(0, 0, 1);
  SB_(1, 1, 0); SB_(1, 1, 1);
  asm volatile("s_waitcnt vmcnt(2)" ::: "memory");  // tile0 landed; tile1-B in flight
  QKV_BAR();

#pragma unroll 1
  for (int i = 0; i < 8; ++i) {
    const int tn = 2 * i + 2;
    const bool st = (i < 7);
    // ph0: buf0 (mh0,c0)
    qkv_ds_a<0, 0>(A0, wm, quad, l15, ar);
    go_ds_b<0>(B0, wn, quad, l15, br);
    SA_(1, 2 * i + 1, 0); SA_(1, 2 * i + 1, 1);
    QKV_BAR(); QKV_LGKM0();
    __builtin_amdgcn_s_setprio(1); go_mf<0, 0>(ar, br, acc); __builtin_amdgcn_s_setprio(0);
    QKV_BAR();
    // ph1: buf0 (mh0,c1) — last LDS reads of B0
    qkv_ds_a<0, 1>(A0, wm, quad, l15, ar);
    go_ds_b<1>(B0, wn, quad, l15, br);
    SA_(1, 2 * i + 1, 2); SA_(1, 2 * i + 1, 3);
    QKV_BAR(); QKV_LGKM0();
    __builtin_amdgcn_s_setprio(1); go_mf<0, 1>(ar, br, acc); __builtin_amdgcn_s_setprio(0);
    QKV_BAR();
    // ph2: buf0 (mh1,c0); br reused from regs; B0 free -> stage into it
    qkv_ds_a<1, 0>(A0, wm, quad, l15, ar);
    if (st) SB_(0, tn, 0);
    QKV_BAR(); QKV_LGKM0();
    __builtin_amdgcn_s_setprio(1); go_mf<1, 0>(ar, br, acc); __builtin_amdgcn_s_setprio(0);
    QKV_BAR();
    // ph3: buf0 (mh1,c1); counted wait: buf1 (A+B of tile 2i+1) landed past here
    qkv_ds_a<1, 1>(A0, wm, quad, l15, ar);
    if (st) SB_(0, tn, 1);
    QKV_BAR(); QKV_LGKM0();
    __builtin_amdgcn_s_setprio(1); go_mf<1, 1>(ar, br, acc); __builtin_amdgcn_s_setprio(0);
    if (st) asm volatile("s_waitcnt vmcnt(2)" ::: "memory");  // leaves ph2/3 B in flight
    else    asm volatile("s_waitcnt vmcnt(0)" ::: "memory");  // last iter: drain all
    QKV_BAR();
    // ph4: buf1 (mh0,c0); A(buf0) free (reads done ph3)
    qkv_ds_a<0, 0>(A1, wm, quad, l15, ar);
    go_ds_b<0>(B1, wn, quad, l15, br);
    if (st) { SA_(0, tn, 0); SA_(0, tn, 1); }
    QKV_BAR(); QKV_LGKM0();
    __builtin_amdgcn_s_setprio(1); go_mf<0, 0>(ar, br, acc); __builtin_amdgcn_s_setprio(0);
    QKV_BAR();
    // ph5: buf1 (mh0,c1) — last LDS reads of B1
    qkv_ds_a<0, 1>(A1, wm, quad, l15, ar);
    go_ds_b<1>(B1, wn, quad, l15, br);
    if (st) { SA_(0, tn, 2); SA_(0, tn, 3); }
    QKV_BAR(); QKV_LGKM0();
    __builtin_amdgcn_s_setprio(1); go_mf<0, 1>(ar, br, acc); __builtin_amdgcn_s_setprio(0);
    QKV_BAR();
    // ph6: buf1 (mh1,c0); br reused; B1 free -> stage into it
    qkv_ds_a<1, 0>(A1, wm, quad, l15, ar);
    if (st) SB_(1, tn + 1, 0);
    QKV_BAR(); QKV_LGKM0();
    __builtin_amdgcn_s_setprio(1); go_mf<1, 0>(ar, br, acc); __builtin_amdgcn_s_setprio(0);
    QKV_BAR();
    // ph7: buf1 (mh1,c1); counted wait: buf0 (A+B of tile 2i+2) landed past here
    qkv_ds_a<1, 1>(A1, wm, quad, l15, ar);
    if (st) SB_(1, tn + 1, 1);
    QKV_BAR(); QKV_LGKM0();
    __builtin_amdgcn_s_setprio(1); go_mf<1, 1>(ar, br, acc); __builtin_amdgcn_s_setprio(0);
    asm volatile("s_waitcnt vmcnt(2)" ::: "memory");
    QKV_BAR();
  }

  // epilogue: Out[mb+r][n] = acc[mi][nj][r] + bO[n]
#pragma unroll
  for (int nj = 0; nj < 2; ++nj) {
    const int n = n0 + wn * 32 + nj * 16 + l15;
    const float bv = bO[n];
#pragma unroll
    for (int mi = 0; mi < 8; ++mi) {
      const int mb = m0 + wm * 128 + mi * 16 + quad * 4;
#pragma unroll
      for (int r = 0; r < 4; ++r)
        Out[(size_t)(mb + r) * 1024 + n] = acc[mi][nj][r] + bv;
    }
  }
}

#undef SA_
#undef SB_
#undef QKV_BAR
#undef QKV_LGKM0

// ---------------- launch ----------------
extern "C" void kernel_launch(void* const* d_in, const int* in_sizes, int n_in,
                              void* d_out, int out_size, void* d_ws, size_t ws_size,
                              hipStream_t stream) {
  const float* x  = (const float*)d_in[0];
  const float* WQ = (const float*)d_in[1];
  const float* bQ = (const float*)d_in[2];
  const float* WK = (const float*)d_in[3];
  const float* bK = (const float*)d_in[4];
  const float* WV = (const float*)d_in[5];
  const float* bV = (const float*)d_in[6];
  const float* WO = (const float*)d_in[7];
  const float* bO = (const float*)d_in[8];
  float* out = (float*)d_out;

  char* ws = (char*)d_ws;
  unsigned short* Xb   = (unsigned short*)(ws);                // 16 MB
  unsigned short* OH   = (unsigned short*)(ws);                // alias (Xb dead)
  unsigned short* Wqkv = (unsigned short*)(ws + 16777216);     // 6 MB
  unsigned short* Wot  = (unsigned short*)(ws + 23068672);     // 2 MB
  unsigned short* Qg   = (unsigned short*)(ws + 25165824);     // 16 MB
  unsigned short* Kg   = (unsigned short*)(ws + 41943040);     // 16 MB
  unsigned int*   Vpg  = (unsigned int*)  (ws + 58720256);     // 16 MB

  prep_all<<<6144, 256, 0, stream>>>(x, WQ, WK, WV, WO, Xb, Wqkv, Wot);

  dim3 g1(32, 16);
  gemm_qkv<<<g1, 512, 0, stream>>>(Xb, Wqkv, bQ, bK, bV, Qg, Kg, Vpg);
  dim3 g2(64, 8);
  flash_attn<<<g2, 256, 0, stream>>>(Qg, Kg, Vpg, OH);
  dim3 g3(32, 8);
  gemm_o<<<g3, 512, 0, stream>>>(OH, Wot, bO, out);
}

// Round 12
// 251.523 us; speedup vs baseline: 1.0672x; 1.0030x over previous
//
#include <hip/hip_runtime.h>
#include <stdint.h>

// Attention fwd: B=4 T=2048 D=1024 H=16 Dh=64.
// R20 = R19 with ONE delta: gemm_qkv register diet to cut the measured spill
//   (R18: WRITE 74.8MB vs 48 real = ~27MB scratch, VGPR 104 vs ~172 live).
//   (a) ar[4][2] -> ar[4]: only one A C-column is live per phase; double-C
//       caching is required for B ONLY (B0 staged-over in ph2/3 while its
//       ph0/1 fragments must survive — A is staged strictly after its last
//       read drains at lgkmcnt(0)). Safe half of R13's transform.
//   (b) staging offset arrays folded to base + compile-time multiples:
//       (u*512+tid)&7 == tid&7 and (u*64+(tid>>3))&7 == (tid>>3)&7, so the
//       swizzle is u-independent: aoff[u]=aoff0+u*65536, dst[u]=tid*8+u*4096.
//   Live ~172 -> ~148. Phase map + vmcnt ledger byte-identical.
// flash: R18 form (MFMA l-sum, 71.2-71.8us). gemm_o: R19 256x128 8-phase.

typedef __attribute__((ext_vector_type(8))) short bf16x8;
typedef __attribute__((ext_vector_type(4))) float f32x4;

#define MFMA32 __builtin_amdgcn_mfma_f32_16x16x32_bf16

#if __has_builtin(__builtin_amdgcn_exp2f)
#define EXP2(x) __builtin_amdgcn_exp2f(x)
#else
#define EXP2(x) exp2f(x)   // host pass only
#endif

__device__ __forceinline__ unsigned short f2bf(float f) {
  union { float f; unsigned int u; } v; v.f = f;
  unsigned int r = v.u + 0x7FFFu + ((v.u >> 16) & 1u);  // RNE
  return (unsigned short)(r >> 16);
}

__device__ __forceinline__ void gl_lds16(const void* g, void* l) {
  __builtin_amdgcn_global_load_lds(
      (const __attribute__((address_space(1))) unsigned int*)g,
      (__attribute__((address_space(3))) unsigned int*)l, 16, 0, 0);
}

// truncating pack of two positive fp32 -> one u32 (two bf16)
__device__ __forceinline__ unsigned packbf2(float lo, float hi) {
  union { float f; unsigned u; } a, b; a.f = lo; b.f = hi;
  return __builtin_amdgcn_perm(b.u, a.u, 0x07060302u);
}

// LDS chunk swizzle for K/V tiles (conflict-free for permuted-row b128 reads)
__device__ __forceinline__ int rho(int r) { return (r & 3) | ((r >> 1) & 4); }

// ---------------- merged prep kernel ----------------
__device__ __forceinline__ void conv8(const float* __restrict__ src,
                                      unsigned short* __restrict__ dst, int i) {
  const float4* sp = (const float4*)src;
  float4 a = sp[2 * i], b = sp[2 * i + 1];
  union { unsigned short u[8]; uint4 v; } o;
  o.u[0] = f2bf(a.x); o.u[1] = f2bf(a.y); o.u[2] = f2bf(a.z); o.u[3] = f2bf(a.w);
  o.u[4] = f2bf(b.x); o.u[5] = f2bf(b.y); o.u[6] = f2bf(b.z); o.u[7] = f2bf(b.w);
  ((uint4*)dst)[i] = o.v;
}

__global__ __launch_bounds__(256) void prep_all(
    const float* __restrict__ x, const float* __restrict__ WQ,
    const float* __restrict__ WK, const float* __restrict__ WV,
    const float* __restrict__ WO, unsigned short* __restrict__ Xb,
    unsigned short* __restrict__ Wqkv, unsigned short* __restrict__ Wot) {
  const int bx = blockIdx.x, t = threadIdx.x;
  if (bx < 4096) {
    conv8(x, Xb, bx * 256 + t);
  } else if (bx < 4608) {
    conv8(WQ, Wqkv, (bx - 4096) * 256 + t);
  } else if (bx < 5120) {
    conv8(WK, Wqkv + 1048576, (bx - 4608) * 256 + t);
  } else if (bx < 5632) {
    conv8(WV, Wqkv + 2097152, (bx - 5120) * 256 + t);
  } else {
    // W_O [16][1024][64] fp32 -> Wot [d][h*64+k] bf16
    int tid = (bx - 5632) * 256 + t;
    int h = tid >> 13, rem = tid & 8191;
    int d = rem >> 3, c = rem & 7;
    const float4* sp = (const float4*)(WO + (size_t)h * 65536 + d * 64 + c * 8);
    float4 a = sp[0], e = sp[1];
    union { unsigned short u[8]; uint4 v; } o;
    o.u[0] = f2bf(a.x); o.u[1] = f2bf(a.y); o.u[2] = f2bf(a.z); o.u[3] = f2bf(a.w);
    o.u[4] = f2bf(e.x); o.u[5] = f2bf(e.y); o.u[6] = f2bf(e.z); o.u[7] = f2bf(e.w);
    *(uint4*)(Wot + (size_t)d * 1024 + h * 64 + c * 8) = o.v;
  }
}

// ---------------- QKV projection: 256x192 tile, 8-phase pipelined ----------------
// LDS ushort layout: A0 @0 (256x64), B0 @16384 (192x64), A1 @28672, B1 @45056.
// Swizzle: element (row,k) at row*64 + ((k>>3)^(row&7))*8 + (k&7)  (involution,
// staged via pre-swizzled global source; measured 0 bank conflicts).
// B REG-CACHE CONTRACT: br[nj][C] holds BOTH K-chunks (loaded ph0/ph1 resp
// ph4/ph5); ph2/3 (ph6/7) reuse br from regs so B buffer can be staged there.
// A needs no double-C: each phase's ar reads drain at that phase's lgkm0,
// strictly before any staging overwrites the A buffer.

template <int MH, int C>
__device__ __forceinline__ void qkv_ds_a(const unsigned short* A, int wm, int quad,
                                         int l15, bf16x8 ar[4]) {
#pragma unroll
  for (int ii = 0; ii < 4; ++ii) {
    int ra = wm * 128 + MH * 64 + ii * 16 + l15;
    ar[ii] = *(const bf16x8*)(A + ra * 64 + (((C * 4 + quad) ^ (ra & 7)) * 8));
  }
}

template <int C>
__device__ __forceinline__ void qkv_ds_b(const unsigned short* B, int wn, int quad,
                                         int l15, bf16x8 br[3][2]) {
#pragma unroll
  for (int nj = 0; nj < 3; ++nj) {
    int rb = wn * 48 + nj * 16 + l15;
    br[nj][C] = *(const bf16x8*)(B + rb * 64 + (((C * 4 + quad) ^ (rb & 7)) * 8));
  }
}

template <int MH, int C>
__device__ __forceinline__ void qkv_mf(const bf16x8 ar[4], const bf16x8 br[3][2],
                                       f32x4 acc[8][3]) {
#pragma unroll
  for (int ii = 0; ii < 4; ++ii)
#pragma unroll
    for (int nj = 0; nj < 3; ++nj)
      acc[MH * 4 + ii][nj] =
          MFMA32(ar[ii], br[nj][C], acc[MH * 4 + ii][nj], 0, 0, 0);
}

#define QKV_BAR() __builtin_amdgcn_s_barrier()
#define QKV_LGKM0() asm volatile("s_waitcnt lgkmcnt(0)" ::: "memory")
// offsets folded: row swizzle is u-independent (see header comment)
#define SA_(bb, kt, u) \
  gl_lds16(Xb + aoff0 + (u)*65536 + (size_t)(kt) * 64, \
           lds + (bb)*28672 + dst0 + (u)*4096)
#define SB_(bb, kt, u) \
  gl_lds16(Wqkv + boff0 + (u)*65536 + (size_t)(kt) * 64, \
           lds + (bb)*28672 + 16384 + dst0 + (u)*4096)

__global__ __launch_bounds__(512, 2) void gemm_qkv(
    const unsigned short* __restrict__ Xb, const unsigned short* __restrict__ Wqkv,
    const float* __restrict__ bQ, const float* __restrict__ bK,
    const float* __restrict__ bV, unsigned short* __restrict__ Qg,
    unsigned short* __restrict__ Kg, unsigned int* __restrict__ Vpg) {
  __shared__ unsigned short lds[57344];  // 112 KB
  const int tid = threadIdx.x, lane = tid & 63, w = tid >> 6;
  const int quad = lane >> 4, l15 = lane & 15;
  const int wm = w >> 2, wn = w & 3;
  const int m0 = blockIdx.x * 256, n0 = blockIdx.y * 192;

  const int srow = tid >> 3;
  const int scl = ((tid & 7) ^ (srow & 7)) * 8;
  const size_t aoff0 = (size_t)(m0 + srow) * 1024 + scl;
  const size_t boff0 = (size_t)(n0 + srow) * 1024 + scl;
  const int dst0 = tid * 8;

  const unsigned short* A0 = lds;
  const unsigned short* B0 = lds + 16384;
  const unsigned short* A1 = lds + 28672;
  const unsigned short* B1 = lds + 45056;

  f32x4 acc[8][3];
#pragma unroll
  for (int i = 0; i < 8; ++i)
#pragma unroll
    for (int j = 0; j < 3; ++j) acc[i][j] = (f32x4){0.f, 0.f, 0.f, 0.f};
  bf16x8 ar[4], br[3][2];

  // prologue: tile0 full -> buf0 (7 loads); tile1 B -> buf1 (3 loads)
  SA_(0, 0, 0); SA_(0, 0, 1); SA_(0, 0, 2); SA_(0, 0, 3);
  SB_(0, 0, 0); SB_(0, 0, 1); SB_(0, 0, 2);
  SB_(1, 1, 0); SB_(1, 1, 1); SB_(1, 1, 2);
  asm volatile("s_waitcnt vmcnt(3)" ::: "memory");  // tile0 landed; tile1-B in flight
  QKV_BAR();

  // 16 K-tiles of 64; iteration i computes tiles 2i (buf0) and 2i+1 (buf1).
  // Staging map (1 half-tile/phase): ph0/1 A(2i+1)->buf1, ph2/3 B(2i+2)->buf0,
  // ph4/5 A(2i+2)->buf0, ph6/7 B(2i+3)->buf1. Counted waits at end of ph3/ph7.
#pragma unroll 1
  for (int i = 0; i < 8; ++i) {
    const int tn = 2 * i + 2;
    const bool st = (i < 7);
    // ph0: buf0 (mh0,c0); loads br[.][0]
    qkv_ds_a<0, 0>(A0, wm, quad, l15, ar);
    qkv_ds_b<0>(B0, wn, quad, l15, br);
    SA_(1, 2 * i + 1, 0); SA_(1, 2 * i + 1, 1);
    QKV_BAR(); QKV_LGKM0();
    __builtin_amdgcn_s_setprio(1); qkv_mf<0, 0>(ar, br, acc); __builtin_amdgcn_s_setprio(0);
    QKV_BAR();
    // ph1: buf0 (mh0,c1); loads br[.][1] — last LDS reads of B0
    qkv_ds_a<0, 1>(A0, wm, quad, l15, ar);
    qkv_ds_b<1>(B0, wn, quad, l15, br);
    SA_(1, 2 * i + 1, 2); SA_(1, 2 * i + 1, 3);
    QKV_BAR(); QKV_LGKM0();
    __builtin_amdgcn_s_setprio(1); qkv_mf<0, 1>(ar, br, acc); __builtin_amdgcn_s_setprio(0);
    QKV_BAR();
    // ph2: buf0 (mh1,c0); br reused from regs; B0 free -> stage into it
    qkv_ds_a<1, 0>(A0, wm, quad, l15, ar);
    if (st) { SB_(0, tn, 0); SB_(0, tn, 1); }
    QKV_BAR(); QKV_LGKM0();
    __builtin_amdgcn_s_setprio(1); qkv_mf<1, 0>(ar, br, acc); __builtin_amdgcn_s_setprio(0);
    QKV_BAR();
    // ph3: buf0 (mh1,c1); counted wait: tile 2i+1 (buf1) landed past here
    qkv_ds_a<1, 1>(A0, wm, quad, l15, ar);
    if (st) SB_(0, tn, 2);
    QKV_BAR(); QKV_LGKM0();
    __builtin_amdgcn_s_setprio(1); qkv_mf<1, 1>(ar, br, acc); __builtin_amdgcn_s_setprio(0);
    if (st) asm volatile("s_waitcnt vmcnt(3)" ::: "memory");  // leaves ph2/3 B in flight
    else    asm volatile("s_waitcnt vmcnt(0)" ::: "memory");  // last iter: drain all
    QKV_BAR();
    // ph4: buf1 (mh0,c0); A(buf0) free (reads done ph3)
    qkv_ds_a<0, 0>(A1, wm, quad, l15, ar);
    qkv_ds_b<0>(B1, wn, quad, l15, br);
    if (st) { SA_(0, tn, 0); SA_(0, tn, 1); }
    QKV_BAR(); QKV_LGKM0();
    __builtin_amdgcn_s_setprio(1); qkv_mf<0, 0>(ar, br, acc); __builtin_amdgcn_s_setprio(0);
    QKV_BAR();
    // ph5: buf1 (mh0,c1) — last LDS reads of B1
    qkv_ds_a<0, 1>(A1, wm, quad, l15, ar);
    qkv_ds_b<1>(B1, wn, quad, l15, br);
    if (st) { SA_(0, tn, 2); SA_(0, tn, 3); }
    QKV_BAR(); QKV_LGKM0();
    __builtin_amdgcn_s_setprio(1); qkv_mf<0, 1>(ar, br, acc); __builtin_amdgcn_s_setprio(0);
    QKV_BAR();
    // ph6: buf1 (mh1,c0); br reused; B1 free -> stage into it
    qkv_ds_a<1, 0>(A1, wm, quad, l15, ar);
    if (st) { SB_(1, tn + 1, 0); SB_(1, tn + 1, 1); }
    QKV_BAR(); QKV_LGKM0();
    __builtin_amdgcn_s_setprio(1); qkv_mf<1, 0>(ar, br, acc); __builtin_amdgcn_s_setprio(0);
    QKV_BAR();
    // ph7: buf1 (mh1,c1); counted wait: tile 2i+2 (buf0) landed past here
    qkv_ds_a<1, 1>(A1, wm, quad, l15, ar);
    if (st) SB_(1, tn + 1, 2);
    QKV_BAR(); QKV_LGKM0();
    __builtin_amdgcn_s_setprio(1); qkv_mf<1, 1>(ar, br, acc); __builtin_amdgcn_s_setprio(0);
    asm volatile("s_waitcnt vmcnt(3)" ::: "memory");  // leaves ph6/7 B in flight
    QKV_BAR();
  }

  // epilogue: C[row = m0+wm*128+mi*16+quad*4+r][col = n0+wn*48+nj*16+l15]
#pragma unroll
  for (int nj = 0; nj < 3; ++nj) {
    const int n_abs = n0 + wn * 48 + nj * 16 + l15;  // 0..3071
    const int type = n_abs >> 10;                    // 0=Q 1=K 2=V
    const int n_in = n_abs & 1023;
    const int h = n_in >> 6, kh = n_in & 63;
    const float bv = ((type == 0) ? bQ : (type == 1) ? bK : bV)[n_in];
#pragma unroll
    for (int mi = 0; mi < 8; ++mi) {
      const int mb = m0 + wm * 128 + mi * 16 + quad * 4;
      const int b = mb >> 11, tb = mb & 2047;
      if (type == 2) {
        uint2 pk;
        pk.x = (unsigned)f2bf(acc[mi][nj][0] + bv) |
               ((unsigned)f2bf(acc[mi][nj][1] + bv) << 16);
        pk.y = (unsigned)f2bf(acc[mi][nj][2] + bv) |
               ((unsigned)f2bf(acc[mi][nj][3] + bv) << 16);
        *(uint2*)(Vpg + ((size_t)(b * 16 + h) * 64 + kh) * 1024 + (tb >> 1)) = pk;
      } else {
        unsigned short* dst =
            ((type == 0) ? Qg : Kg) + ((size_t)(b * 16 + h) * 2048 + tb) * 64 + kh;
        // Q pre-scaled by 1/sqrt(Dh) * log2(e) so flash uses exp2 directly
        const float sc = (type == 0) ? 0.18033688011112042f : 1.0f;
        dst[0]   = f2bf((acc[mi][nj][0] + bv) * sc);
        dst[64]  = f2bf((acc[mi][nj][1] + bv) * sc);
        dst[128] = f2bf((acc[mi][nj][2] + bv) * sc);
        dst[192] = f2bf((acc[mi][nj][3] + bv) * sc);
      }
    }
  }
}

#undef SA_
#undef SB_

// ---------------- flash attention (R9 form + setprio + MFMA l-sum) ----------
__device__ __forceinline__ void stage_kv(const unsigned short* __restrict__ Kb,
                                         const unsigned int* __restrict__ Vb,
                                         unsigned short* smem, int tid, int s0, int b) {
#pragma unroll
  for (int u = 0; u < 2; ++u) {
    int s = u * 256 + tid, row = s >> 3, g = (s & 7) ^ rho(row);
    gl_lds16(Kb + (size_t)(s0 + row) * 64 + g * 8, smem + b * 8192 + s * 8);
    gl_lds16(Vb + (size_t)row * 1024 + (s0 >> 1) + g * 4,
             smem + b * 8192 + 4096 + s * 8);
  }
}

// block: 256 q-rows of one (b,h); wave owns 64 q; k-tiles of 64, double-buffered.
// grid (bh=64, qt=8): all q-tiles of one bh on one XCD -> K/V L2-local.
__global__ __launch_bounds__(256, 2) void flash_attn(
    const unsigned short* __restrict__ Qg, const unsigned short* __restrict__ Kg,
    const unsigned int* __restrict__ Vpg, unsigned short* __restrict__ OH) {
  __shared__ unsigned short smem[16384];  // 32KB: [K0 8K][V0 8K][K1 8K][V1 8K]
  const int tid = threadIdx.x, lane = tid & 63, w = tid >> 6;
  const int quad = lane >> 4, l15 = lane & 15;
  const int bh = blockIdx.x, qt = blockIdx.y;

  const unsigned short* Qb = Qg + ((size_t)bh * 2048 + qt * 256) * 64;
  const unsigned short* Kb = Kg + (size_t)bh * 2048 * 64;
  const unsigned int*  Vb = Vpg + (size_t)bh * 64 * 1024;

  // stage Q (256 rows = 32KB, whole smem) — dead before tile 0
#pragma unroll
  for (int u = 0; u < 8; ++u) {
    int s = u * 256 + tid, row = s >> 3;
    gl_lds16(Qb + row * 64 + ((s & 7) ^ (row & 7)) * 8, smem + s * 8);
  }
  __syncthreads();

  bf16x8 qf[4][2];  // B-operand Q frags, hoisted for whole kernel
#pragma unroll
  for (int qi = 0; qi < 4; ++qi) {
    int row = w * 64 + qi * 16 + l15;
#pragma unroll
    for (int c = 0; c < 2; ++c)
      qf[qi][c] = *(const bf16x8*)(smem + row * 64 + (((c * 4 + quad) ^ (row & 7)) * 8));
  }
  __syncthreads();  // all waves done reading Q; safe to overwrite with K0/V0

  stage_kv(Kb, Vb, smem, tid, 0, 0);

  // ones matrix (bf16 1.0 = 0x3F80) as PV B-operand for l row-sums
  union { uint4 q; bf16x8 v; } onesu;
  onesu.q = make_uint4(0x3F803F80u, 0x3F803F80u, 0x3F803F80u, 0x3F803F80u);
  const bf16x8 ones = onesu.v;

  f32x4 o[4][4];
  f32x4 lacc[4];  // l row-sums, same C/D layout as o: row 4*quad+r, col l15
#pragma unroll
  for (int qi = 0; qi < 4; ++qi) {
    lacc[qi] = (f32x4){0.f, 0.f, 0.f, 0.f};
#pragma unroll
    for (int nj = 0; nj < 4; ++nj) o[qi][nj] = (f32x4){0.f, 0.f, 0.f, 0.f};
  }

  for (int t = 0; t < 32; ++t) {
    __syncthreads();  // drains tile-t staging
    if (t < 31) stage_kv(Kb, Vb, smem, tid, (t + 1) * 64, (t + 1) & 1);
    const unsigned short* Kd = smem + (t & 1) * 8192;
    const unsigned short* Vd = Kd + 4096;

#pragma unroll
    for (int blk = 0; blk < 2; ++blk) {
      // V B-frags: Vt[dh = nj*16+l15][s = blk*32 + quad*8 .. +7] — one b128 each
      bf16x8 vb[4];
#pragma unroll
      for (int nj = 0; nj < 4; ++nj) {
        int vrow = nj * 16 + l15;
        vb[nj] = *(const bf16x8*)(Vd + vrow * 64 + (((blk * 4 + quad) ^ rho(vrow)) * 8));
      }
      union { unsigned u[4]; bf16x8 v; } pa[4];
#pragma unroll
      for (int v = 0; v < 2; ++v) {
        // permuted K rows: C/D row m maps to s = blk*32 + 8*quad + 4*v + reg
        int krow = blk * 32 + 8 * (l15 >> 2) + 4 * v + (l15 & 3);
        const unsigned short* kr = Kd + krow * 64;
        bf16x8 ka0 = *(const bf16x8*)(kr + ((quad ^ rho(krow)) * 8));
        bf16x8 ka1 = *(const bf16x8*)(kr + (((4 + quad) ^ rho(krow)) * 8));
#pragma unroll
        for (int qi = 0; qi < 4; ++qi) {
          f32x4 S = (f32x4){0.f, 0.f, 0.f, 0.f};
          S = MFMA32(ka0, qf[qi][0], S, 0, 0, 0);
          S = MFMA32(ka1, qf[qi][1], S, 0, 0, 0);
          float e0 = EXP2(S[0]), e1 = EXP2(S[1]), e2 = EXP2(S[2]), e3 = EXP2(S[3]);
          pa[qi].u[2 * v] = packbf2(e0, e1);
          pa[qi].u[2 * v + 1] = packbf2(e2, e3);
        }
      }
      // PV + l row-sums on the MFMA pipe (T5 setprio around cluster)
      __builtin_amdgcn_s_setprio(1);
#pragma unroll
      for (int qi = 0; qi < 4; ++qi) {
        lacc[qi] = MFMA32(pa[qi].v, ones, lacc[qi], 0, 0, 0);
#pragma unroll
        for (int nj = 0; nj < 4; ++nj)
          o[qi][nj] = MFMA32(pa[qi].v, vb[nj], o[qi][nj], 0, 0, 0);
      }
      __builtin_amdgcn_s_setprio(0);
    }
  }

  // normalize + store: lacc[qi][r] is the row-sum for trow's own lane — no shfl
  const int b = bh >> 4, h = bh & 15;
#pragma unroll
  for (int qi = 0; qi < 4; ++qi) {
#pragma unroll
    for (int r = 0; r < 4; ++r) {
      float lr = 1.0f / lacc[qi][r];
      int trow = qt * 256 + w * 64 + qi * 16 + 4 * quad + r;
#pragma unroll
      for (int nj = 0; nj < 4; ++nj) {
        int col = h * 64 + nj * 16 + l15;
        OH[((size_t)b * 2048 + trow) * 1024 + col] = f2bf(o[qi][nj][r] * lr);
      }
    }
  }
}

// ---------------- output projection: 256x128 tile, 8-phase pipelined ---------
// Clone of the qkv template with BN=128: A 256x64 (32KB), B 128x64 (16KB),
// double-buffered = 96KB LDS. Loads/tile: A=4, B=2. Counted vmcnt(2) at
// ph3/ph7 (ledger: ph3 queue [B1:2][A1:4][B0:2] -> drain 6, leave 2).
// 8 waves 2Mx4N, per-wave 128x32, acc[8][2]. Grid (32,8)=256 = 1 block/CU.

template <int C>
__device__ __forceinline__ void go_ds_b(const unsigned short* B, int wn, int quad,
                                        int l15, bf16x8 br[2][2]) {
#pragma unroll
  for (int nj = 0; nj < 2; ++nj) {
    int rb = wn * 32 + nj * 16 + l15;
    br[nj][C] = *(const bf16x8*)(B + rb * 64 + (((C * 4 + quad) ^ (rb & 7)) * 8));
  }
}

template <int MH, int C>
__device__ __forceinline__ void go_ds_a(const unsigned short* A, int wm, int quad,
                                        int l15, bf16x8 ar[4]) {
#pragma unroll
  for (int ii = 0; ii < 4; ++ii) {
    int ra = wm * 128 + MH * 64 + ii * 16 + l15;
    ar[ii] = *(const bf16x8*)(A + ra * 64 + (((C * 4 + quad) ^ (ra & 7)) * 8));
  }
}

template <int MH, int C>
__device__ __forceinline__ void go_mf(const bf16x8 ar[4], const bf16x8 br[2][2],
                                      f32x4 acc[8][2]) {
#pragma unroll
  for (int ii = 0; ii < 4; ++ii)
#pragma unroll
    for (int nj = 0; nj < 2; ++nj)
      acc[MH * 4 + ii][nj] =
          MFMA32(ar[ii], br[nj][C], acc[MH * 4 + ii][nj], 0, 0, 0);
}

#define SA_(bb, kt, u) \
  gl_lds16(OHm + (size_t)aoff[u] + (size_t)(kt) * 64, lds + (bb)*24576 + adst[u])
#define SB_(bb, kt, u) \
  gl_lds16(Wot + (size_t)boff[u] + (size_t)(kt) * 64, lds + (bb)*24576 + 16384 + bdst[u])

__global__ __launch_bounds__(512, 2) void gemm_o(
    const unsigned short* __restrict__ OHm, const unsigned short* __restrict__ Wot,
    const float* __restrict__ bO, float* __restrict__ Out) {
  __shared__ unsigned short lds[49152];  // 96 KB
  const int tid = threadIdx.x, lane = tid & 63, w = tid >> 6;
  const int quad = lane >> 4, l15 = lane & 15;
  const int wm = w >> 2, wn = w & 3;
  const int m0 = blockIdx.x * 256, n0 = blockIdx.y * 128;

  int aoff[4], adst[4];
#pragma unroll
  for (int u = 0; u < 4; ++u) {
    int s = u * 512 + tid, row = s >> 3;
    aoff[u] = (m0 + row) * 1024 + (((s & 7) ^ (row & 7)) * 8);
    adst[u] = s * 8;
  }
  int boff[2], bdst[2];
#pragma unroll
  for (int u = 0; u < 2; ++u) {
    int s = u * 512 + tid, row = s >> 3;
    boff[u] = (n0 + row) * 1024 + (((s & 7) ^ (row & 7)) * 8);
    bdst[u] = s * 8;
  }

  const unsigned short* A0 = lds;
  const unsigned short* B0 = lds + 16384;
  const unsigned short* A1 = lds + 24576;
  const unsigned short* B1 = lds + 40960;

  f32x4 acc[8][2];
#pragma unroll
  for (int i = 0; i < 8; ++i)
#pragma unroll
    for (int j = 0; j < 2; ++j) acc[i][j] = (f32x4){0.f, 0.f, 0.f, 0.f};
  bf16x8 ar[4], br[2][2];

  // prologue: tile0 full -> buf0 (6 loads); tile1 B -> buf1 (2 loads)
  SA_(0, 0, 0); SA_(0, 0, 1); SA_(0, 0, 2); SA_(0, 0, 3);
  SB_(0, 0, 0); SB_(0, 0, 1);
  SB_(1, 1, 0); SB_(1, 1, 1);
  asm volatile("s_waitcnt vmcnt(2)" ::: "memory");  // tile0 landed; tile1-B in flight
  QKV_BAR();

#pragma unroll 1
  for (int i = 0; i < 8; ++i) {
    const int tn = 2 * i + 2;
    const bool st = (i < 7);
    // ph0: buf0 (mh0,c0)
    go_ds_a<0, 0>(A0, wm, quad, l15, ar);
    go_ds_b<0>(B0, wn, quad, l15, br);
    SA_(1, 2 * i + 1, 0); SA_(1, 2 * i + 1, 1);
    QKV_BAR(); QKV_LGKM0();
    __builtin_amdgcn_s_setprio(1); go_mf<0, 0>(ar, br, acc); __builtin_amdgcn_s_setprio(0);
    QKV_BAR();
    // ph1: buf0 (mh0,c1) — last LDS reads of B0
    go_ds_a<0, 1>(A0, wm, quad, l15, ar);
    go_ds_b<1>(B0, wn, quad, l15, br);
    SA_(1, 2 * i + 1, 2); SA_(1, 2 * i + 1, 3);
    QKV_BAR(); QKV_LGKM0();
    __builtin_amdgcn_s_setprio(1); go_mf<0, 1>(ar, br, acc); __builtin_amdgcn_s_setprio(0);
    QKV_BAR();
    // ph2: buf0 (mh1,c0); br reused from regs; B0 free -> stage into it
    go_ds_a<1, 0>(A0, wm, quad, l15, ar);
    if (st) SB_(0, tn, 0);
    QKV_BAR(); QKV_LGKM0();
    __builtin_amdgcn_s_setprio(1); go_mf<1, 0>(ar, br, acc); __builtin_amdgcn_s_setprio(0);
    QKV_BAR();
    // ph3: buf0 (mh1,c1); counted wait: buf1 (A+B of tile 2i+1) landed past here
    go_ds_a<1, 1>(A0, wm, quad, l15, ar);
    if (st) SB_(0, tn, 1);
    QKV_BAR(); QKV_LGKM0();
    __builtin_amdgcn_s_setprio(1); go_mf<1, 1>(ar, br, acc); __builtin_amdgcn_s_setprio(0);
    if (st) asm volatile("s_waitcnt vmcnt(2)" ::: "memory");  // leaves ph2/3 B in flight
    else    asm volatile("s_waitcnt vmcnt(0)" ::: "memory");  // last iter: drain all
    QKV_BAR();
    // ph4: buf1 (mh0,c0); A(buf0) free (reads done ph3)
    go_ds_a<0, 0>(A1, wm, quad, l15, ar);
    go_ds_b<0>(B1, wn, quad, l15, br);
    if (st) { SA_(0, tn, 0); SA_(0, tn, 1); }
    QKV_BAR(); QKV_LGKM0();
    __builtin_amdgcn_s_setprio(1); go_mf<0, 0>(ar, br, acc); __builtin_amdgcn_s_setprio(0);
    QKV_BAR();
    // ph5: buf1 (mh0,c1) — last LDS reads of B1
    go_ds_a<0, 1>(A1, wm, quad, l15, ar);
    go_ds_b<1>(B1, wn, quad, l15, br);
    if (st) { SA_(0, tn, 2); SA_(0, tn, 3); }
    QKV_BAR(); QKV_LGKM0();
    __builtin_amdgcn_s_setprio(1); go_mf<0, 1>(ar, br, acc); __builtin_amdgcn_s_setprio(0);
    QKV_BAR();
    // ph6: buf1 (mh1,c0); br reused; B1 free -> stage into it
    go_ds_a<1, 0>(A1, wm, quad, l15, ar);
    if (st) SB_(1, tn + 1, 0);
    QKV_BAR(); QKV_LGKM0();
    __builtin_amdgcn_s_setprio(1); go_mf<1, 0>(ar, br, acc); __builtin_amdgcn_s_setprio(0);
    QKV_BAR();
    // ph7: buf1 (mh1,c1); counted wait: buf0 (A+B of tile 2i+2) landed past here
    go_ds_a<1, 1>(A1, wm, quad, l15, ar);
    if (st) SB_(1, tn + 1, 1);
    QKV_BAR(); QKV_LGKM0();
    __builtin_amdgcn_s_setprio(1); go_mf<1, 1>(ar, br, acc); __builtin_amdgcn_s_setprio(0);
    asm volatile("s_waitcnt vmcnt(2)" ::: "memory");
    QKV_BAR();
  }

  // epilogue: Out[mb+r][n] = acc[mi][nj][r] + bO[n]
#pragma unroll
  for (int nj = 0; nj < 2; ++nj) {
    const int n = n0 + wn * 32 + nj * 16 + l15;
    const float bv = bO[n];
#pragma unroll
    for (int mi = 0; mi < 8; ++mi) {
      const int mb = m0 + wm * 128 + mi * 16 + quad * 4;
#pragma unroll
      for (int r = 0; r < 4; ++r)
        Out[(size_t)(mb + r) * 1024 + n] = acc[mi][nj][r] + bv;
    }
  }
}

#undef SA_
#undef SB_
#undef QKV_BAR
#undef QKV_LGKM0

// ---------------- launch ----------------
extern "C" void kernel_launch(void* const* d_in, const int* in_sizes, int n_in,
                              void* d_out, int out_size, void* d_ws, size_t ws_size,
                              hipStream_t stream) {
  const float* x  = (const float*)d_in[0];
  const float* WQ = (const float*)d_in[1];
  const float* bQ = (const float*)d_in[2];
  const float* WK = (const float*)d_in[3];
  const float* bK = (const float*)d_in[4];
  const float* WV = (const float*)d_in[5];
  const float* bV = (const float*)d_in[6];
  const float* WO = (const float*)d_in[7];
  const float* bO = (const float*)d_in[8];
  float* out = (float*)d_out;

  char* ws = (char*)d_ws;
  unsigned short* Xb   = (unsigned short*)(ws);                // 16 MB
  unsigned short* OH   = (unsigned short*)(ws);                // alias (Xb dead)
  unsigned short* Wqkv = (unsigned short*)(ws + 16777216);     // 6 MB
  unsigned short* Wot  = (unsigned short*)(ws + 23068672);     // 2 MB
  unsigned short* Qg   = (unsigned short*)(ws + 25165824);     // 16 MB
  unsigned short* Kg   = (unsigned short*)(ws + 41943040);     // 16 MB
  unsigned int*   Vpg  = (unsigned int*)  (ws + 58720256);     // 16 MB

  prep_all<<<6144, 256, 0, stream>>>(x, WQ, WK, WV, WO, Xb, Wqkv, Wot);

  dim3 g1(32, 16);
  gemm_qkv<<<g1, 512, 0, stream>>>(Xb, Wqkv, bQ, bK, bV, Qg, Kg, Vpg);
  dim3 g2(64, 8);
  flash_attn<<<g2, 256, 0, stream>>>(Qg, Kg, Vpg, OH);
  dim3 g3(32, 8);
  gemm_o<<<g3, 512, 0, stream>>>(OH, Wot, bO, out);
}